// Round 4
// baseline (373.424 us; speedup 1.0000x reference)
//
#include <hip/hip_runtime.h>
#include <hip/hip_bf16.h>
#include <stdint.h>

typedef _Float16 f16;
typedef _Float16 f16x8 __attribute__((ext_vector_type(8)));
typedef _Float16 f16v4 __attribute__((ext_vector_type(4)));
typedef float f32x4 __attribute__((ext_vector_type(4)));

#define LDK 72  // LDS row stride (fp16 elems) for BK=64 tiles: 144B rows, 2-way bank alias (free)

// ---------- edge access: handles int32 or int64 storage of edge_index ----------
__device__ __forceinline__ int edge_at(const void* ep, int isI64, long long idx) {
  if (isI64) return (int)((const long long*)ep)[idx];
  return ((const int*)ep)[idx];
}

__global__ void detect_kernel(const unsigned int* __restrict__ e, int* __restrict__ flag) {
  __shared__ int any;
  if (threadIdx.x == 0) any = 0;
  __syncthreads();
  for (int idx = 1 + 2 * (int)threadIdx.x; idx < 4096; idx += 512) {
    if (e[idx] != 0u) any = 1;
  }
  __syncthreads();
  if (threadIdx.x == 0) flag[0] = any ? 0 : 1;
}

__global__ void deg_kernel(const void* __restrict__ ep, const int* __restrict__ flag,
                           int* __restrict__ indeg, int E) {
  int e = blockIdx.x * blockDim.x + threadIdx.x;
  if (e >= E) return;
  int i64 = flag[0];
  int d = edge_at(ep, i64, (long long)E + e);
  atomicAdd(&indeg[d], 1);
}

__global__ void dinv_kernel(const int* __restrict__ indeg, float* __restrict__ dinv, int n) {
  int i = blockIdx.x * blockDim.x + threadIdx.x;
  if (i < n) dinv[i] = rsqrtf((float)(indeg[i] + 1));
}

// ---------- prefix scan: wave-shuffle based, 3 barriers per 1024-chunk ----------
__global__ __launch_bounds__(1024) void prefix_kernel(const int* __restrict__ indeg,
                                                      int* __restrict__ rowptr, int n) {
  __shared__ int wsum[16];
  int t = threadIdx.x;
  int lane = t & 63;
  int w = t >> 6;
  int carry = 0;
  if (t == 0) rowptr[0] = 0;
  for (int base = 0; base < n; base += 1024) {
    int i = base + t;
    int v = (i < n) ? indeg[i] : 0;
    int sv = v;
#pragma unroll
    for (int off = 1; off < 64; off <<= 1) {
      int u = __shfl_up(sv, off, 64);
      if (lane >= off) sv += u;
    }
    if (lane == 63) wsum[w] = sv;
    __syncthreads();
    if (w == 0 && lane < 16) {
      int ws = wsum[lane];
#pragma unroll
      for (int off = 1; off < 16; off <<= 1) {
        int u = __shfl_up(ws, off, 64);
        if (lane >= off) ws += u;
      }
      wsum[lane] = ws;
    }
    __syncthreads();
    int woff = (w > 0) ? wsum[w - 1] : 0;
    if (i < n) rowptr[i + 1] = carry + woff + sv;
    carry += wsum[15];
    __syncthreads();
  }
}

__global__ void scatter_kernel(const void* __restrict__ ep, const int* __restrict__ flag,
                               const int* __restrict__ rowptr, int* __restrict__ cursor,
                               int* __restrict__ colsrc, int E) {
  int e = blockIdx.x * blockDim.x + threadIdx.x;
  if (e >= E) return;
  int i64 = flag[0];
  int s = edge_at(ep, i64, (long long)e);
  int d = edge_at(ep, i64, (long long)E + e);
  int pos = atomicAdd(&cursor[d], 1);
  colsrc[rowptr[d] + pos] = s;
}

// ---------- agg1: wave per node, lane holds float4 (256 feats = 64 lanes x 4) ----------
__global__ __launch_bounds__(256) void agg1_kernel(const float* __restrict__ x,
                                                   const float* __restrict__ dinv,
                                                   const int* __restrict__ rowptr,
                                                   const int* __restrict__ colsrc,
                                                   f16* __restrict__ xa, int n) {
  int wave = threadIdx.x >> 6;
  int lane = threadIdx.x & 63;
  int i = blockIdx.x * 4 + wave;
  if (i >= n) return;
  const float4* xp = (const float4*)x;  // row = 64 float4
  float di = dinv[i];
  float4 s = xp[(size_t)i * 64 + lane];
  float ax = di * s.x, ay = di * s.y, az = di * s.z, aw = di * s.w;
  float bx = 0.f, by = 0.f, bz = 0.f, bw = 0.f;
  int beg = rowptr[i], end = rowptr[i + 1];
  int j = beg;
  for (; j + 1 < end; j += 2) {
    int s0 = colsrc[j], s1 = colsrc[j + 1];
    float w0 = dinv[s0], w1 = dinv[s1];
    float4 v0 = xp[(size_t)s0 * 64 + lane];
    float4 v1 = xp[(size_t)s1 * 64 + lane];
    ax += w0 * v0.x; ay += w0 * v0.y; az += w0 * v0.z; aw += w0 * v0.w;
    bx += w1 * v1.x; by += w1 * v1.y; bz += w1 * v1.z; bw += w1 * v1.w;
  }
  if (j < end) {
    int s0 = colsrc[j];
    float w0 = dinv[s0];
    float4 v0 = xp[(size_t)s0 * 64 + lane];
    ax += w0 * v0.x; ay += w0 * v0.y; az += w0 * v0.z; aw += w0 * v0.w;
  }
  f16v4 r;
  r[0] = (f16)(di * (ax + bx));
  r[1] = (f16)(di * (ay + by));
  r[2] = (f16)(di * (az + bz));
  r[3] = (f16)(di * (aw + bw));
  *(f16v4*)&xa[(size_t)i * 256 + lane * 4] = r;
}

// ---------- agg2: wave per node, lane holds f16x8 (400 feats = 50 lanes x 8) ----------
__global__ __launch_bounds__(256) void agg2_kernel(const f16* __restrict__ g,
                                                   const float* __restrict__ dinv,
                                                   const int* __restrict__ rowptr,
                                                   const int* __restrict__ colsrc,
                                                   const float* __restrict__ bias,
                                                   float* __restrict__ out, int n, int F) {
  int wave = threadIdx.x >> 6;
  int lane = threadIdx.x & 63;
  int i = blockIdx.x * 4 + wave;
  if (i >= n) return;
  int base = lane * 8;
  if (base >= F) return;
  float di = dinv[i];
  f16x8 sv = *(const f16x8*)&g[(size_t)i * F + base];
  float a[8], b[8];
#pragma unroll
  for (int r = 0; r < 8; ++r) { a[r] = di * (float)sv[r]; b[r] = 0.f; }
  int beg = rowptr[i], end = rowptr[i + 1];
  int j = beg;
  for (; j + 1 < end; j += 2) {
    int s0 = colsrc[j], s1 = colsrc[j + 1];
    float w0 = dinv[s0], w1 = dinv[s1];
    f16x8 v0 = *(const f16x8*)&g[(size_t)s0 * F + base];
    f16x8 v1 = *(const f16x8*)&g[(size_t)s1 * F + base];
#pragma unroll
    for (int r = 0; r < 8; ++r) { a[r] += w0 * (float)v0[r]; b[r] += w1 * (float)v1[r]; }
  }
  if (j < end) {
    int s0 = colsrc[j];
    float w0 = dinv[s0];
    f16x8 v0 = *(const f16x8*)&g[(size_t)s0 * F + base];
#pragma unroll
    for (int r = 0; r < 8; ++r) a[r] += w0 * (float)v0[r];
  }
  float4 o0, o1;
  float4 bv0 = *(const float4*)&bias[base];
  float4 bv1 = *(const float4*)&bias[base + 4];
  o0.x = di * (a[0] + b[0]) + bv0.x; o0.y = di * (a[1] + b[1]) + bv0.y;
  o0.z = di * (a[2] + b[2]) + bv0.z; o0.w = di * (a[3] + b[3]) + bv0.w;
  o1.x = di * (a[4] + b[4]) + bv1.x; o1.y = di * (a[5] + b[5]) + bv1.y;
  o1.z = di * (a[6] + b[6]) + bv1.z; o1.w = di * (a[7] + b[7]) + bv1.w;
  *(float4*)&out[(size_t)i * F + base] = o0;
  *(float4*)&out[(size_t)i * F + base + 4] = o1;
}

// ---------- weight cast + transpose: W[K][N] -> Wt[N][K] fp16 ----------
__global__ void castT_kernel(const float* __restrict__ W, f16* __restrict__ Wt, int K, int N) {
  int idx = blockIdx.x * 256 + threadIdx.x;
  if (idx >= K * N) return;
  int k = idx / N;
  int nn = idx - k * N;
  Wt[(size_t)nn * K + k] = (f16)W[idx];
}

// ---------- GEMM1: C = A[MxK] @ B[NxK]^T, +bias +relu, fp16 out ----------
// 128x128 tile, BK=64, 4 waves each 64x64 via 4x4 of 16x16x32 MFMAs.
__global__ __launch_bounds__(256) void gemm1_f16(
    const f16* __restrict__ A, const f16* __restrict__ B,
    const float* __restrict__ bias, f16* __restrict__ C,
    int M, int N, int K) {
  __shared__ __align__(16) f16 sA[128 * LDK];
  __shared__ __align__(16) f16 sB[128 * LDK];
  const int m0 = blockIdx.y * 128;
  const int n0 = blockIdx.x * 128;
  const int lane = threadIdx.x & 63;
  const int wave = threadIdx.x >> 6;
  const int wm = (wave & 1) * 64;
  const int wn = (wave >> 1) * 64;
  const int lrow = lane & 15;
  const int koff = (lane >> 4) * 8;

  f32x4 acc[4][4];
#pragma unroll
  for (int i = 0; i < 4; ++i)
#pragma unroll
    for (int j = 0; j < 4; ++j) acc[i][j] = (f32x4)(0.f);

  for (int k0 = 0; k0 < K; k0 += 64) {
    // stage: each tile 128 rows x 64 k fp16 = 1024 16B-chunks, 4/thread
#pragma unroll
    for (int i = 0; i < 4; ++i) {
      int c = (int)threadIdx.x + i * 256;
      int row = c >> 3;
      int kq = (c & 7) * 8;
      uint4 v = make_uint4(0, 0, 0, 0);
      int gr = m0 + row;
      if (gr < M) v = *(const uint4*)&A[(size_t)gr * K + k0 + kq];
      *(uint4*)&sA[row * LDK + kq] = v;
      v = make_uint4(0, 0, 0, 0);
      int gn = n0 + row;
      if (gn < N) v = *(const uint4*)&B[(size_t)gn * K + k0 + kq];
      *(uint4*)&sB[row * LDK + kq] = v;
    }
    __syncthreads();
#pragma unroll
    for (int kk = 0; kk < 2; ++kk) {
      f16x8 af[4], bf[4];
#pragma unroll
      for (int i = 0; i < 4; ++i) {
        af[i] = *(const f16x8*)&sA[(wm + i * 16 + lrow) * LDK + koff + kk * 32];
        bf[i] = *(const f16x8*)&sB[(wn + i * 16 + lrow) * LDK + koff + kk * 32];
      }
#pragma unroll
      for (int i = 0; i < 4; ++i)
#pragma unroll
        for (int j = 0; j < 4; ++j)
          acc[i][j] = __builtin_amdgcn_mfma_f32_16x16x32_f16(af[i], bf[j], acc[i][j], 0, 0, 0);
    }
    __syncthreads();
  }

  const int crow = (lane >> 4) * 4;
  const int ccol = lane & 15;
#pragma unroll
  for (int j = 0; j < 4; ++j) {
    int gcol = n0 + wn + j * 16 + ccol;
    if (gcol >= N) continue;
    float bv = bias[gcol];
#pragma unroll
    for (int i = 0; i < 4; ++i) {
#pragma unroll
      for (int r = 0; r < 4; ++r) {
        int grow = m0 + wm + i * 16 + crow + r;
        if (grow >= M) continue;
        float v = fmaxf(acc[i][j][r] + bv, 0.f);
        C[(size_t)grow * N + gcol] = (f16)v;
      }
    }
  }
}

// ---------- GEMM2: C = A[MxK] @ B[NxK]^T, fp16 out, tile 128x80 (zero waste at N=400) ----------
// BK=64, 4 waves each 32 rows x 80 cols (2x5 of 16x16 MFMAs). XCD swizzle groups the
// 5 n-tiles of one m-strip onto one XCD for A-strip L2 reuse.
__global__ __launch_bounds__(256) void gemm2_f16(
    const f16* __restrict__ A, const f16* __restrict__ B, f16* __restrict__ C,
    int M, int N, int K) {
  __shared__ __align__(16) f16 sA[128 * LDK];
  __shared__ __align__(16) f16 sB[80 * LDK];

  const int mtc = (M + 127) >> 7;
  const int ntc = (N + 79) / 80;
  const int fullm = mtc & ~7;
  const int full = fullm * ntc;
  int idf = blockIdx.x;
  int mt, nt;
  if (idf < full) {
    int gsz = 8 * ntc;
    int grp = idf / gsz;
    int r = idf - grp * gsz;
    mt = grp * 8 + (r & 7);
    nt = r >> 3;
  } else {
    int r = idf - full;
    int rem = mtc - fullm;
    mt = fullm + r % rem;
    nt = r / rem;
  }
  const int m0 = mt * 128;
  const int n0 = nt * 80;
  const int lane = threadIdx.x & 63;
  const int wave = threadIdx.x >> 6;
  const int wm = wave * 32;
  const int lrow = lane & 15;
  const int koff = (lane >> 4) * 8;

  f32x4 acc[2][5];
#pragma unroll
  for (int i = 0; i < 2; ++i)
#pragma unroll
    for (int j = 0; j < 5; ++j) acc[i][j] = (f32x4)(0.f);

  for (int k0 = 0; k0 < K; k0 += 64) {
    // sA: 128x64 = 1024 chunks, 4/thread
#pragma unroll
    for (int i = 0; i < 4; ++i) {
      int c = (int)threadIdx.x + i * 256;
      int row = c >> 3;
      int kq = (c & 7) * 8;
      uint4 v = make_uint4(0, 0, 0, 0);
      int gr = m0 + row;
      if (gr < M) v = *(const uint4*)&A[(size_t)gr * K + k0 + kq];
      *(uint4*)&sA[row * LDK + kq] = v;
    }
    // sB: 80x64 = 640 chunks
#pragma unroll
    for (int i = 0; i < 3; ++i) {
      int c = (int)threadIdx.x + i * 256;
      if (c < 640) {
        int row = c >> 3;
        int kq = (c & 7) * 8;
        uint4 v = make_uint4(0, 0, 0, 0);
        int gn = n0 + row;
        if (gn < N) v = *(const uint4*)&B[(size_t)gn * K + k0 + kq];
        *(uint4*)&sB[row * LDK + kq] = v;
      }
    }
    __syncthreads();
#pragma unroll
    for (int kk = 0; kk < 2; ++kk) {
      f16x8 af[2], bf[5];
#pragma unroll
      for (int i = 0; i < 2; ++i)
        af[i] = *(const f16x8*)&sA[(wm + i * 16 + lrow) * LDK + koff + kk * 32];
#pragma unroll
      for (int j = 0; j < 5; ++j)
        bf[j] = *(const f16x8*)&sB[(j * 16 + lrow) * LDK + koff + kk * 32];
#pragma unroll
      for (int i = 0; i < 2; ++i)
#pragma unroll
        for (int j = 0; j < 5; ++j)
          acc[i][j] = __builtin_amdgcn_mfma_f32_16x16x32_f16(af[i], bf[j], acc[i][j], 0, 0, 0);
    }
    __syncthreads();
  }

  const int crow = (lane >> 4) * 4;
  const int ccol = lane & 15;
#pragma unroll
  for (int j = 0; j < 5; ++j) {
    int gcol = n0 + j * 16 + ccol;
    if (gcol >= N) continue;
#pragma unroll
    for (int i = 0; i < 2; ++i) {
#pragma unroll
      for (int r = 0; r < 4; ++r) {
        int grow = m0 + wm + i * 16 + crow + r;
        if (grow >= M) continue;
        C[(size_t)grow * N + gcol] = (f16)acc[i][j][r];
      }
    }
  }
}

extern "C" void kernel_launch(void* const* d_in, const int* in_sizes, int n_in,
                              void* d_out, int out_size, void* d_ws, size_t ws_size,
                              hipStream_t stream) {
  const float* x = (const float*)d_in[0];
  const void* edges = d_in[1];
  const float* W1 = (const float*)d_in[2];
  const float* b1 = (const float*)d_in[3];
  const float* W2 = (const float*)d_in[4];
  const float* b2 = (const float*)d_in[5];
  float* out = (float*)d_out;

  const int N1 = in_sizes[3];       // 1600
  const int N2 = in_sizes[5];       // 400
  const int K1 = in_sizes[2] / N1;  // 256
  const int K2 = in_sizes[4] / N2;  // 1600
  const int n = in_sizes[0] / K1;   // 20000
  const int E = in_sizes[1] / 2;    // 320000

  char* ws = (char*)d_ws;
  size_t o = 0;
  auto take = [&](size_t bytes) {
    char* p = ws + o;
    o += (bytes + 255) & ~(size_t)255;
    return p;
  };
  int* indeg = (int*)take((size_t)n * 4);
  int* cursor = (int*)take((size_t)n * 4);
  int* flag = (int*)take(4);
  size_t zero_bytes = o;
  int* rowptr = (int*)take((size_t)(n + 1) * 4);
  int* colsrc = (int*)take((size_t)E * 4);
  float* dinv = (float*)take((size_t)n * 4);
  f16* xa = (f16*)take((size_t)n * K1 * 2);    // 10 MB
  f16* w1t = (f16*)take((size_t)K1 * N1 * 2);  // 0.8 MB
  f16* w2t = (f16*)take((size_t)K2 * N2 * 2);  // 1.3 MB
  f16* h = (f16*)take((size_t)n * N1 * 2);     // 64 MB
  f16* g = (f16*)take((size_t)n * N2 * 2);     // 16 MB

  hipMemsetAsync(d_ws, 0, zero_bytes, stream);

  detect_kernel<<<1, 256, 0, stream>>>((const unsigned int*)edges, flag);
  deg_kernel<<<(E + 255) / 256, 256, 0, stream>>>(edges, flag, indeg, E);
  dinv_kernel<<<(n + 255) / 256, 256, 0, stream>>>(indeg, dinv, n);
  prefix_kernel<<<1, 1024, 0, stream>>>(indeg, rowptr, n);
  scatter_kernel<<<(E + 255) / 256, 256, 0, stream>>>(edges, flag, rowptr, cursor, colsrc, E);

  castT_kernel<<<(K1 * N1 + 255) / 256, 256, 0, stream>>>(W1, w1t, K1, N1);
  castT_kernel<<<(K2 * N2 + 255) / 256, 256, 0, stream>>>(W2, w2t, K2, N2);

  // Layer 1: aggregate at 256 dims (fp16 out), then GEMM (+b1, relu, fp16 out)
  agg1_kernel<<<(n + 3) / 4, 256, 0, stream>>>(x, dinv, rowptr, colsrc, xa, n);
  {
    dim3 grid((N1 + 127) / 128, (n + 127) / 128);
    gemm1_f16<<<grid, 256, 0, stream>>>(xa, w1t, b1, h, n, N1, K1);
  }
  // Layer 2: GEMM (fp16 out, 128x80 tiles), then aggregate (+b2, fp32 out)
  {
    int mtc = (n + 127) / 128;
    int ntc = (N2 + 79) / 80;
    gemm2_f16<<<mtc * ntc, 256, 0, stream>>>(h, w2t, g, n, N2, K2);
  }
  agg2_kernel<<<(n + 3) / 4, 256, 0, stream>>>(g, dinv, rowptr, colsrc, b2, out, n, N2);
}

// Round 5
// 302.518 us; speedup vs baseline: 1.2344x; 1.2344x over previous
//
#include <hip/hip_runtime.h>
#include <hip/hip_bf16.h>
#include <stdint.h>

typedef _Float16 f16;
typedef _Float16 f16x8 __attribute__((ext_vector_type(8)));
typedef _Float16 f16v4 __attribute__((ext_vector_type(4)));
typedef float f32x4 __attribute__((ext_vector_type(4)));

// async 16B global->LDS (wave-uniform LDS base + lane*16)
__device__ __forceinline__ void gload_lds16(const f16* g, f16* l) {
  __builtin_amdgcn_global_load_lds(
      (const __attribute__((address_space(1))) void*)g,
      (__attribute__((address_space(3))) void*)l, 16, 0, 0);
}

// ---------- edge access: handles int32 or int64 storage of edge_index ----------
__device__ __forceinline__ int edge_at(const void* ep, int isI64, long long idx) {
  if (isI64) return (int)((const long long*)ep)[idx];
  return ((const int*)ep)[idx];
}

__global__ void detect_kernel(const unsigned int* __restrict__ e, int* __restrict__ flag) {
  __shared__ int any;
  if (threadIdx.x == 0) any = 0;
  __syncthreads();
  for (int idx = 1 + 2 * (int)threadIdx.x; idx < 4096; idx += 512) {
    if (e[idx] != 0u) any = 1;
  }
  __syncthreads();
  if (threadIdx.x == 0) flag[0] = any ? 0 : 1;
}

__global__ void deg_kernel(const void* __restrict__ ep, const int* __restrict__ flag,
                           int* __restrict__ indeg, int E) {
  int e = blockIdx.x * blockDim.x + threadIdx.x;
  if (e >= E) return;
  int i64 = flag[0];
  int d = edge_at(ep, i64, (long long)E + e);
  atomicAdd(&indeg[d], 1);
}

__global__ void dinv_kernel(const int* __restrict__ indeg, float* __restrict__ dinv, int n) {
  int i = blockIdx.x * blockDim.x + threadIdx.x;
  if (i < n) dinv[i] = rsqrtf((float)(indeg[i] + 1));
}

// ---------- prefix scan: wave-shuffle based ----------
__global__ __launch_bounds__(1024) void prefix_kernel(const int* __restrict__ indeg,
                                                      int* __restrict__ rowptr, int n) {
  __shared__ int wsum[16];
  int t = threadIdx.x;
  int lane = t & 63;
  int w = t >> 6;
  int carry = 0;
  if (t == 0) rowptr[0] = 0;
  for (int base = 0; base < n; base += 1024) {
    int i = base + t;
    int v = (i < n) ? indeg[i] : 0;
    int sv = v;
#pragma unroll
    for (int off = 1; off < 64; off <<= 1) {
      int u = __shfl_up(sv, off, 64);
      if (lane >= off) sv += u;
    }
    if (lane == 63) wsum[w] = sv;
    __syncthreads();
    if (w == 0 && lane < 16) {
      int ws = wsum[lane];
#pragma unroll
      for (int off = 1; off < 16; off <<= 1) {
        int u = __shfl_up(ws, off, 64);
        if (lane >= off) ws += u;
      }
      wsum[lane] = ws;
    }
    __syncthreads();
    int woff = (w > 0) ? wsum[w - 1] : 0;
    if (i < n) rowptr[i + 1] = carry + woff + sv;
    carry += wsum[15];
    __syncthreads();
  }
}

__global__ void scatter_kernel(const void* __restrict__ ep, const int* __restrict__ flag,
                               const int* __restrict__ rowptr, int* __restrict__ cursor,
                               int* __restrict__ colsrc, int E) {
  int e = blockIdx.x * blockDim.x + threadIdx.x;
  if (e >= E) return;
  int i64 = flag[0];
  int s = edge_at(ep, i64, (long long)e);
  int d = edge_at(ep, i64, (long long)E + e);
  int pos = atomicAdd(&cursor[d], 1);
  colsrc[rowptr[d] + pos] = s;
}

// ---------- agg1: wave per node, lane holds float4 (256 feats), 4-way unrolled ----------
__global__ __launch_bounds__(256) void agg1_kernel(const float* __restrict__ x,
                                                   const float* __restrict__ dinv,
                                                   const int* __restrict__ rowptr,
                                                   const int* __restrict__ colsrc,
                                                   f16* __restrict__ xa, int n) {
  int wave = threadIdx.x >> 6;
  int lane = threadIdx.x & 63;
  int i = blockIdx.x * 4 + wave;
  if (i >= n) return;
  const float4* xp = (const float4*)x;
  float di = dinv[i];
  float4 s = xp[(size_t)i * 64 + lane];
  float ax = di * s.x, ay = di * s.y, az = di * s.z, aw = di * s.w;
  float bx = 0.f, by = 0.f, bz = 0.f, bw = 0.f;
  int beg = rowptr[i], end = rowptr[i + 1];
  int j = beg;
  for (; j + 3 < end; j += 4) {
    int s0 = colsrc[j], s1 = colsrc[j + 1], s2 = colsrc[j + 2], s3 = colsrc[j + 3];
    float w0 = dinv[s0], w1 = dinv[s1], w2 = dinv[s2], w3 = dinv[s3];
    float4 v0 = xp[(size_t)s0 * 64 + lane];
    float4 v1 = xp[(size_t)s1 * 64 + lane];
    float4 v2 = xp[(size_t)s2 * 64 + lane];
    float4 v3 = xp[(size_t)s3 * 64 + lane];
    ax += w0 * v0.x + w2 * v2.x; ay += w0 * v0.y + w2 * v2.y;
    az += w0 * v0.z + w2 * v2.z; aw += w0 * v0.w + w2 * v2.w;
    bx += w1 * v1.x + w3 * v3.x; by += w1 * v1.y + w3 * v3.y;
    bz += w1 * v1.z + w3 * v3.z; bw += w1 * v1.w + w3 * v3.w;
  }
  for (; j < end; ++j) {
    int s0 = colsrc[j];
    float w0 = dinv[s0];
    float4 v0 = xp[(size_t)s0 * 64 + lane];
    ax += w0 * v0.x; ay += w0 * v0.y; az += w0 * v0.z; aw += w0 * v0.w;
  }
  f16v4 r;
  r[0] = (f16)(di * (ax + bx));
  r[1] = (f16)(di * (ay + by));
  r[2] = (f16)(di * (az + bz));
  r[3] = (f16)(di * (aw + bw));
  *(f16v4*)&xa[(size_t)i * 256 + lane * 4] = r;
}

// ---------- agg2: wave per node, lane holds f16x8 (400 feats = 50 lanes x 8) ----------
__global__ __launch_bounds__(256) void agg2_kernel(const f16* __restrict__ g,
                                                   const float* __restrict__ dinv,
                                                   const int* __restrict__ rowptr,
                                                   const int* __restrict__ colsrc,
                                                   const float* __restrict__ bias,
                                                   float* __restrict__ out, int n, int F) {
  int wave = threadIdx.x >> 6;
  int lane = threadIdx.x & 63;
  int i = blockIdx.x * 4 + wave;
  if (i >= n) return;
  int base = lane * 8;
  if (base >= F) return;
  float di = dinv[i];
  f16x8 sv = *(const f16x8*)&g[(size_t)i * F + base];
  float a[8], b[8];
#pragma unroll
  for (int r = 0; r < 8; ++r) { a[r] = di * (float)sv[r]; b[r] = 0.f; }
  int beg = rowptr[i], end = rowptr[i + 1];
  int j = beg;
  for (; j + 1 < end; j += 2) {
    int s0 = colsrc[j], s1 = colsrc[j + 1];
    float w0 = dinv[s0], w1 = dinv[s1];
    f16x8 v0 = *(const f16x8*)&g[(size_t)s0 * F + base];
    f16x8 v1 = *(const f16x8*)&g[(size_t)s1 * F + base];
#pragma unroll
    for (int r = 0; r < 8; ++r) { a[r] += w0 * (float)v0[r]; b[r] += w1 * (float)v1[r]; }
  }
  if (j < end) {
    int s0 = colsrc[j];
    float w0 = dinv[s0];
    f16x8 v0 = *(const f16x8*)&g[(size_t)s0 * F + base];
#pragma unroll
    for (int r = 0; r < 8; ++r) a[r] += w0 * (float)v0[r];
  }
  float4 o0, o1;
  float4 bv0 = *(const float4*)&bias[base];
  float4 bv1 = *(const float4*)&bias[base + 4];
  o0.x = di * (a[0] + b[0]) + bv0.x; o0.y = di * (a[1] + b[1]) + bv0.y;
  o0.z = di * (a[2] + b[2]) + bv0.z; o0.w = di * (a[3] + b[3]) + bv0.w;
  o1.x = di * (a[4] + b[4]) + bv1.x; o1.y = di * (a[5] + b[5]) + bv1.y;
  o1.z = di * (a[6] + b[6]) + bv1.z; o1.w = di * (a[7] + b[7]) + bv1.w;
  *(float4*)&out[(size_t)i * F + base] = o0;
  *(float4*)&out[(size_t)i * F + base + 4] = o1;
}

// ---------- weight cast + transpose: W[K][N] -> Wt[N][K] fp16 ----------
__global__ void castT_kernel(const float* __restrict__ W, f16* __restrict__ Wt, int K, int N) {
  int idx = blockIdx.x * 256 + threadIdx.x;
  if (idx >= K * N) return;
  int k = idx / N;
  int nn = idx - k * N;
  Wt[(size_t)nn * K + k] = (f16)W[idx];
}

// ---------- GEMM1: C = A[MxK] @ B[NxK]^T, +bias +relu, fp16 out ----------
// 128x128 tile, BK=64, async global_load_lds staging w/ XOR chunk swizzle,
// LDS-repacked coalesced epilogue.
__global__ __launch_bounds__(256) void gemm1_f16(
    const f16* __restrict__ A, const f16* __restrict__ B,
    const float* __restrict__ bias, f16* __restrict__ C,
    int M, int N, int K) {
  __shared__ __align__(16) f16 smem[2 * 128 * 64];  // 32 KB: sA | sB, also epilogue buffer
  f16* sA = smem;
  f16* sB = smem + 128 * 64;
  const int m0 = blockIdx.y * 128;
  const int n0 = blockIdx.x * 128;
  const int lane = threadIdx.x & 63;
  const int wave = threadIdx.x >> 6;
  const int wm = (wave & 1) * 64;
  const int wn = (wave >> 1) * 64;
  const int lrow = lane & 15;
  const int quad = lane >> 4;

  f32x4 acc[4][4];
#pragma unroll
  for (int i = 0; i < 4; ++i)
#pragma unroll
    for (int j = 0; j < 4; ++j) acc[i][j] = (f32x4)(0.f);

  for (int k0 = 0; k0 < K; k0 += 64) {
    // stage A,B: 1024 16B-chunks each; chunk ch=(i*4+wave)*64+lane; LDS linear,
    // global chunk index XOR-swizzled by row&7.
#pragma unroll
    for (int i = 0; i < 4; ++i) {
      int ch = (i * 4 + wave) * 64 + lane;
      int r = ch >> 3;
      int cg = (ch & 7) ^ (r & 7);
      int gr = min(m0 + r, M - 1);
      gload_lds16(&A[(size_t)gr * K + k0 + cg * 8], &sA[(size_t)(i * 4 + wave) * 512]);
      int gn = min(n0 + r, N - 1);
      gload_lds16(&B[(size_t)gn * K + k0 + cg * 8], &sB[(size_t)(i * 4 + wave) * 512]);
    }
    __syncthreads();
#pragma unroll
    for (int kk = 0; kk < 2; ++kk) {
      f16x8 af[4], bf[4];
      int cg = quad + kk * 4;
#pragma unroll
      for (int i = 0; i < 4; ++i) {
        int ra = wm + i * 16 + lrow;
        af[i] = *(const f16x8*)&sA[ra * 64 + ((cg ^ (ra & 7)) * 8)];
        int rb = wn + i * 16 + lrow;
        bf[i] = *(const f16x8*)&sB[rb * 64 + ((cg ^ (rb & 7)) * 8)];
      }
#pragma unroll
      for (int i = 0; i < 4; ++i)
#pragma unroll
        for (int j = 0; j < 4; ++j)
          acc[i][j] = __builtin_amdgcn_mfma_f32_16x16x32_f16(af[i], bf[j], acc[i][j], 0, 0, 0);
    }
    __syncthreads();
  }

  // epilogue: acc -> smem (f16 tile [128][128]) -> coalesced dwordx4 stores
  const int crow = quad * 4;
  const int ccol = lane & 15;
#pragma unroll
  for (int j = 0; j < 4; ++j) {
    int col = wn + j * 16 + ccol;
    int gcol = n0 + col;
    float bv = (gcol < N) ? bias[gcol] : 0.f;
#pragma unroll
    for (int i = 0; i < 4; ++i) {
#pragma unroll
      for (int r = 0; r < 4; ++r) {
        int row = wm + i * 16 + crow + r;
        smem[row * 128 + col] = (f16)fmaxf(acc[i][j][r] + bv, 0.f);
      }
    }
  }
  __syncthreads();
#pragma unroll
  for (int i = 0; i < 8; ++i) {
    int ch = i * 256 + (int)threadIdx.x;
    int r = ch >> 4;
    int cc = ch & 15;
    int grow = m0 + r;
    int gcol = n0 + cc * 8;
    if (grow < M && gcol < N)
      *(uint4*)&C[(size_t)grow * N + gcol] = *(const uint4*)&smem[r * 128 + cc * 8];
  }
}

// ---------- GEMM2: C = A[MxK] @ B[NxK]^T, fp16 out, tile 128x80 (N=400 exact) ----------
__global__ __launch_bounds__(256) void gemm2_f16(
    const f16* __restrict__ A, const f16* __restrict__ B, f16* __restrict__ C,
    int M, int N, int K) {
  __shared__ __align__(16) f16 smem[128 * 64 + 80 * 64];  // 26 KB
  f16* sA = smem;
  f16* sB = smem + 128 * 64;

  const int mtc = (M + 127) >> 7;
  const int ntc = (N + 79) / 80;
  const int fullm = mtc & ~7;
  const int full = fullm * ntc;
  int idf = blockIdx.x;
  int mt, nt;
  if (idf < full) {
    int gsz = 8 * ntc;
    int grp = idf / gsz;
    int r = idf - grp * gsz;
    mt = grp * 8 + (r & 7);
    nt = r >> 3;
  } else {
    int r = idf - full;
    int rem = mtc - fullm;
    mt = fullm + r % rem;
    nt = r / rem;
  }
  const int m0 = mt * 128;
  const int n0 = nt * 80;
  const int lane = threadIdx.x & 63;
  const int wave = threadIdx.x >> 6;
  const int wm = wave * 32;
  const int lrow = lane & 15;
  const int quad = lane >> 4;

  f32x4 acc[2][5];
#pragma unroll
  for (int i = 0; i < 2; ++i)
#pragma unroll
    for (int j = 0; j < 5; ++j) acc[i][j] = (f32x4)(0.f);

  for (int k0 = 0; k0 < K; k0 += 64) {
#pragma unroll
    for (int i = 0; i < 4; ++i) {
      int ch = (i * 4 + wave) * 64 + lane;
      int r = ch >> 3;
      int cg = (ch & 7) ^ (r & 7);
      int gr = min(m0 + r, M - 1);
      gload_lds16(&A[(size_t)gr * K + k0 + cg * 8], &sA[(size_t)(i * 4 + wave) * 512]);
    }
#pragma unroll
    for (int i = 0; i < 3; ++i) {
      if (i * 4 + wave < 10) {  // 640 chunks, wave-uniform guard
        int ch = (i * 4 + wave) * 64 + lane;
        int r = ch >> 3;
        int cg = (ch & 7) ^ (r & 7);
        gload_lds16(&B[(size_t)(n0 + r) * K + k0 + cg * 8], &sB[(size_t)(i * 4 + wave) * 512]);
      }
    }
    __syncthreads();
#pragma unroll
    for (int kk = 0; kk < 2; ++kk) {
      f16x8 af[2], bf[5];
      int cg = quad + kk * 4;
#pragma unroll
      for (int i = 0; i < 2; ++i) {
        int ra = wm + i * 16 + lrow;
        af[i] = *(const f16x8*)&sA[ra * 64 + ((cg ^ (ra & 7)) * 8)];
      }
#pragma unroll
      for (int j = 0; j < 5; ++j) {
        int rb = j * 16 + lrow;
        bf[j] = *(const f16x8*)&sB[rb * 64 + ((cg ^ (rb & 7)) * 8)];
      }
#pragma unroll
      for (int i = 0; i < 2; ++i)
#pragma unroll
        for (int j = 0; j < 5; ++j)
          acc[i][j] = __builtin_amdgcn_mfma_f32_16x16x32_f16(af[i], bf[j], acc[i][j], 0, 0, 0);
    }
    __syncthreads();
  }

  // epilogue: acc -> smem (f16 tile [128][80]) -> coalesced dwordx4 stores
  const int crow = quad * 4;
  const int ccol = lane & 15;
#pragma unroll
  for (int j = 0; j < 5; ++j) {
    int col = j * 16 + ccol;
#pragma unroll
    for (int i = 0; i < 2; ++i) {
#pragma unroll
      for (int r = 0; r < 4; ++r) {
        int row = wm + i * 16 + crow + r;
        smem[row * 80 + col] = (f16)acc[i][j][r];
      }
    }
  }
  __syncthreads();
#pragma unroll
  for (int i = 0; i < 5; ++i) {
    int ch = i * 256 + (int)threadIdx.x;  // of 1280 chunks (10 per row)
    int r = ch / 10;
    int rem = ch - 10 * r;
    int grow = m0 + r;
    if (grow < M)
      *(uint4*)&C[(size_t)grow * N + n0 + rem * 8] = *(const uint4*)&smem[r * 80 + rem * 8];
  }
}

extern "C" void kernel_launch(void* const* d_in, const int* in_sizes, int n_in,
                              void* d_out, int out_size, void* d_ws, size_t ws_size,
                              hipStream_t stream) {
  const float* x = (const float*)d_in[0];
  const void* edges = d_in[1];
  const float* W1 = (const float*)d_in[2];
  const float* b1 = (const float*)d_in[3];
  const float* W2 = (const float*)d_in[4];
  const float* b2 = (const float*)d_in[5];
  float* out = (float*)d_out;

  const int N1 = in_sizes[3];       // 1600
  const int N2 = in_sizes[5];       // 400
  const int K1 = in_sizes[2] / N1;  // 256
  const int K2 = in_sizes[4] / N2;  // 1600
  const int n = in_sizes[0] / K1;   // 20000
  const int E = in_sizes[1] / 2;    // 320000

  char* ws = (char*)d_ws;
  size_t o = 0;
  auto take = [&](size_t bytes) {
    char* p = ws + o;
    o += (bytes + 255) & ~(size_t)255;
    return p;
  };
  int* indeg = (int*)take((size_t)n * 4);
  int* cursor = (int*)take((size_t)n * 4);
  int* flag = (int*)take(4);
  size_t zero_bytes = o;
  int* rowptr = (int*)take((size_t)(n + 1) * 4);
  int* colsrc = (int*)take((size_t)E * 4);
  float* dinv = (float*)take((size_t)n * 4);
  f16* xa = (f16*)take((size_t)n * K1 * 2);    // 10 MB
  f16* w1t = (f16*)take((size_t)K1 * N1 * 2);  // 0.8 MB
  f16* w2t = (f16*)take((size_t)K2 * N2 * 2);  // 1.3 MB
  f16* h = (f16*)take((size_t)n * N1 * 2);     // 64 MB
  f16* g = (f16*)take((size_t)n * N2 * 2);     // 16 MB

  hipMemsetAsync(d_ws, 0, zero_bytes, stream);

  detect_kernel<<<1, 256, 0, stream>>>((const unsigned int*)edges, flag);
  deg_kernel<<<(E + 255) / 256, 256, 0, stream>>>(edges, flag, indeg, E);
  dinv_kernel<<<(n + 255) / 256, 256, 0, stream>>>(indeg, dinv, n);
  prefix_kernel<<<1, 1024, 0, stream>>>(indeg, rowptr, n);
  scatter_kernel<<<(E + 255) / 256, 256, 0, stream>>>(edges, flag, rowptr, cursor, colsrc, E);

  castT_kernel<<<(K1 * N1 + 255) / 256, 256, 0, stream>>>(W1, w1t, K1, N1);
  castT_kernel<<<(K2 * N2 + 255) / 256, 256, 0, stream>>>(W2, w2t, K2, N2);

  // Layer 1: aggregate at 256 dims (fp16 out), then GEMM (+b1, relu, fp16 out)
  agg1_kernel<<<(n + 3) / 4, 256, 0, stream>>>(x, dinv, rowptr, colsrc, xa, n);
  {
    dim3 grid((N1 + 127) / 128, (n + 127) / 128);
    gemm1_f16<<<grid, 256, 0, stream>>>(xa, w1t, b1, h, n, N1, K1);
  }
  // Layer 2: GEMM (fp16 out, 128x80 tiles), then aggregate (+b2, fp32 out)
  {
    int mtc = (n + 127) / 128;
    int ntc = (N2 + 79) / 80;
    gemm2_f16<<<mtc * ntc, 256, 0, stream>>>(h, w2t, g, n, N2, K2);
  }
  agg2_kernel<<<(n + 3) / 4, 256, 0, stream>>>(g, dinv, rowptr, colsrc, b2, out, n, N2);
}

// Round 6
// 291.946 us; speedup vs baseline: 1.2791x; 1.0362x over previous
//
#include <hip/hip_runtime.h>
#include <hip/hip_bf16.h>
#include <stdint.h>

typedef _Float16 f16;
typedef _Float16 f16x8 __attribute__((ext_vector_type(8)));
typedef _Float16 f16v4 __attribute__((ext_vector_type(4)));
typedef float f32x4 __attribute__((ext_vector_type(4)));

// async 16B global->LDS (wave-uniform LDS base + lane*16)
__device__ __forceinline__ void gload_lds16(const f16* g, f16* l) {
  __builtin_amdgcn_global_load_lds(
      (const __attribute__((address_space(1))) void*)g,
      (__attribute__((address_space(3))) void*)l, 16, 0, 0);
}

// ---------- edge access: handles int32 or int64 storage of edge_index ----------
__device__ __forceinline__ int edge_at(const void* ep, int isI64, long long idx) {
  if (isI64) return (int)((const long long*)ep)[idx];
  return ((const int*)ep)[idx];
}

__global__ void detect_kernel(const unsigned int* __restrict__ e, int* __restrict__ flag) {
  __shared__ int any;
  if (threadIdx.x == 0) any = 0;
  __syncthreads();
  for (int idx = 1 + 2 * (int)threadIdx.x; idx < 4096; idx += 512) {
    if (e[idx] != 0u) any = 1;
  }
  __syncthreads();
  if (threadIdx.x == 0) flag[0] = any ? 0 : 1;
}

__global__ void deg_kernel(const void* __restrict__ ep, const int* __restrict__ flag,
                           int* __restrict__ indeg, int E) {
  int e = blockIdx.x * blockDim.x + threadIdx.x;
  if (e >= E) return;
  int i64 = flag[0];
  int d = edge_at(ep, i64, (long long)E + e);
  atomicAdd(&indeg[d], 1);
}

// ---------- prefix scan (wave-shuffle) + fused dinv ----------
__global__ __launch_bounds__(1024) void prefix_kernel(const int* __restrict__ indeg,
                                                      int* __restrict__ rowptr,
                                                      float* __restrict__ dinv, int n) {
  __shared__ int wsum[16];
  int t = threadIdx.x;
  int lane = t & 63;
  int w = t >> 6;
  int carry = 0;
  if (t == 0) rowptr[0] = 0;
  for (int base = 0; base < n; base += 1024) {
    int i = base + t;
    int v = (i < n) ? indeg[i] : 0;
    if (i < n) dinv[i] = rsqrtf((float)(v + 1));
    int sv = v;
#pragma unroll
    for (int off = 1; off < 64; off <<= 1) {
      int u = __shfl_up(sv, off, 64);
      if (lane >= off) sv += u;
    }
    if (lane == 63) wsum[w] = sv;
    __syncthreads();
    if (w == 0 && lane < 16) {
      int ws = wsum[lane];
#pragma unroll
      for (int off = 1; off < 16; off <<= 1) {
        int u = __shfl_up(ws, off, 64);
        if (lane >= off) ws += u;
      }
      wsum[lane] = ws;
    }
    __syncthreads();
    int woff = (w > 0) ? wsum[w - 1] : 0;
    if (i < n) rowptr[i + 1] = carry + woff + sv;
    carry += wsum[15];
    __syncthreads();
  }
}

__global__ void scatter_kernel(const void* __restrict__ ep, const int* __restrict__ flag,
                               const int* __restrict__ rowptr, int* __restrict__ cursor,
                               int* __restrict__ colsrc, int E) {
  int e = blockIdx.x * blockDim.x + threadIdx.x;
  if (e >= E) return;
  int i64 = flag[0];
  int s = edge_at(ep, i64, (long long)e);
  int d = edge_at(ep, i64, (long long)E + e);
  int pos = atomicAdd(&cursor[d], 1);
  colsrc[rowptr[d] + pos] = s;
}

// ---------- xs = (f16)(dinv[row] * x): 4 floats per thread ----------
__global__ void xcast_kernel(const float* __restrict__ x, const float* __restrict__ dinv,
                             f16* __restrict__ xs, int n) {
  int c = blockIdx.x * 256 + threadIdx.x;  // chunk of 4 elems; 64 chunks/row
  if (c >= n * 64) return;
  int row = c >> 6;
  float d = dinv[row];
  float4 v = ((const float4*)x)[c];
  f16v4 r;
  r[0] = (f16)(d * v.x);
  r[1] = (f16)(d * v.y);
  r[2] = (f16)(d * v.z);
  r[3] = (f16)(d * v.w);
  ((f16v4*)xs)[c] = r;
}

// ---------- agg1: wave per node over fp16 xs (dinv-premultiplied), 4-way unrolled ----------
// xa[i] = (f16)( dinv[i] * (xs[i] + sum_s xs[s]) )
__global__ __launch_bounds__(256) void agg1_kernel(const f16* __restrict__ xs,
                                                   const float* __restrict__ dinv,
                                                   const int* __restrict__ rowptr,
                                                   const int* __restrict__ colsrc,
                                                   f16* __restrict__ xa, int n) {
  int wave = threadIdx.x >> 6;
  int lane = threadIdx.x & 63;
  int i = blockIdx.x * 4 + wave;
  if (i >= n) return;
  const f16v4* xp = (const f16v4*)xs;  // row = 64 f16v4 chunks
  float di = dinv[i];
  f16v4 s = xp[(size_t)i * 64 + lane];
  float a0 = (float)s[0], a1 = (float)s[1], a2 = (float)s[2], a3 = (float)s[3];
  float b0 = 0.f, b1 = 0.f, b2 = 0.f, b3 = 0.f;
  int beg = rowptr[i], end = rowptr[i + 1];
  int j = beg;
  for (; j + 3 < end; j += 4) {
    int s0 = colsrc[j], s1 = colsrc[j + 1], s2 = colsrc[j + 2], s3 = colsrc[j + 3];
    f16v4 v0 = xp[(size_t)s0 * 64 + lane];
    f16v4 v1 = xp[(size_t)s1 * 64 + lane];
    f16v4 v2 = xp[(size_t)s2 * 64 + lane];
    f16v4 v3 = xp[(size_t)s3 * 64 + lane];
    a0 += (float)v0[0] + (float)v2[0]; a1 += (float)v0[1] + (float)v2[1];
    a2 += (float)v0[2] + (float)v2[2]; a3 += (float)v0[3] + (float)v2[3];
    b0 += (float)v1[0] + (float)v3[0]; b1 += (float)v1[1] + (float)v3[1];
    b2 += (float)v1[2] + (float)v3[2]; b3 += (float)v1[3] + (float)v3[3];
  }
  for (; j < end; ++j) {
    int s0 = colsrc[j];
    f16v4 v0 = xp[(size_t)s0 * 64 + lane];
    a0 += (float)v0[0]; a1 += (float)v0[1]; a2 += (float)v0[2]; a3 += (float)v0[3];
  }
  f16v4 r;
  r[0] = (f16)(di * (a0 + b0));
  r[1] = (f16)(di * (a1 + b1));
  r[2] = (f16)(di * (a2 + b2));
  r[3] = (f16)(di * (a3 + b3));
  *(f16v4*)&xa[(size_t)i * 256 + lane * 4] = r;
}

// ---------- agg2: wave per node over dinv-premultiplied gs, 4-way unrolled ----------
// out[i] = dinv[i] * (gs[i] + sum_s gs[s]) + bias
__global__ __launch_bounds__(256) void agg2_kernel(const f16* __restrict__ gs,
                                                   const float* __restrict__ dinv,
                                                   const int* __restrict__ rowptr,
                                                   const int* __restrict__ colsrc,
                                                   const float* __restrict__ bias,
                                                   float* __restrict__ out, int n, int F) {
  int wave = threadIdx.x >> 6;
  int lane = threadIdx.x & 63;
  int i = blockIdx.x * 4 + wave;
  if (i >= n) return;
  int base = lane * 8;
  if (base >= F) return;
  float di = dinv[i];
  f16x8 sv = *(const f16x8*)&gs[(size_t)i * F + base];
  float a[8], b[8];
#pragma unroll
  for (int r = 0; r < 8; ++r) { a[r] = (float)sv[r]; b[r] = 0.f; }
  int beg = rowptr[i], end = rowptr[i + 1];
  int j = beg;
  for (; j + 3 < end; j += 4) {
    int s0 = colsrc[j], s1 = colsrc[j + 1], s2 = colsrc[j + 2], s3 = colsrc[j + 3];
    f16x8 v0 = *(const f16x8*)&gs[(size_t)s0 * F + base];
    f16x8 v1 = *(const f16x8*)&gs[(size_t)s1 * F + base];
    f16x8 v2 = *(const f16x8*)&gs[(size_t)s2 * F + base];
    f16x8 v3 = *(const f16x8*)&gs[(size_t)s3 * F + base];
#pragma unroll
    for (int r = 0; r < 8; ++r) {
      a[r] += (float)v0[r] + (float)v2[r];
      b[r] += (float)v1[r] + (float)v3[r];
    }
  }
  for (; j < end; ++j) {
    int s0 = colsrc[j];
    f16x8 v0 = *(const f16x8*)&gs[(size_t)s0 * F + base];
#pragma unroll
    for (int r = 0; r < 8; ++r) a[r] += (float)v0[r];
  }
  float4 o0, o1;
  float4 bv0 = *(const float4*)&bias[base];
  float4 bv1 = *(const float4*)&bias[base + 4];
  o0.x = di * (a[0] + b[0]) + bv0.x; o0.y = di * (a[1] + b[1]) + bv0.y;
  o0.z = di * (a[2] + b[2]) + bv0.z; o0.w = di * (a[3] + b[3]) + bv0.w;
  o1.x = di * (a[4] + b[4]) + bv1.x; o1.y = di * (a[5] + b[5]) + bv1.y;
  o1.z = di * (a[6] + b[6]) + bv1.z; o1.w = di * (a[7] + b[7]) + bv1.w;
  *(float4*)&out[(size_t)i * F + base] = o0;
  *(float4*)&out[(size_t)i * F + base + 4] = o1;
}

// ---------- both weight casts in one launch: W[K][N] -> Wt[N][K] fp16 ----------
__global__ void castT_kernel(const float* __restrict__ W1, f16* __restrict__ W1t, int K1, int N1,
                             const float* __restrict__ W2, f16* __restrict__ W2t, int K2, int N2) {
  int idx = blockIdx.x * 256 + threadIdx.x;
  int t1 = K1 * N1;
  if (idx < t1) {
    int k = idx / N1;
    int nn = idx - k * N1;
    W1t[(size_t)nn * K1 + k] = (f16)W1[idx];
  } else {
    idx -= t1;
    if (idx < K2 * N2) {
      int k = idx / N2;
      int nn = idx - k * N2;
      W2t[(size_t)nn * K2 + k] = (f16)W2[idx];
    }
  }
}

// ---------- GEMM1: C = A[MxK] @ B[NxK]^T, +bias +relu, fp16 out ----------
// 128x128 tile, BK=64, async global_load_lds staging w/ XOR chunk swizzle,
// LDS-repacked coalesced epilogue.
__global__ __launch_bounds__(256) void gemm1_f16(
    const f16* __restrict__ A, const f16* __restrict__ B,
    const float* __restrict__ bias, f16* __restrict__ C,
    int M, int N, int K) {
  __shared__ __align__(16) f16 smem[2 * 128 * 64];  // 32 KB: sA | sB, also epilogue buffer
  f16* sA = smem;
  f16* sB = smem + 128 * 64;
  const int m0 = blockIdx.y * 128;
  const int n0 = blockIdx.x * 128;
  const int lane = threadIdx.x & 63;
  const int wave = threadIdx.x >> 6;
  const int wm = (wave & 1) * 64;
  const int wn = (wave >> 1) * 64;
  const int lrow = lane & 15;
  const int quad = lane >> 4;

  f32x4 acc[4][4];
#pragma unroll
  for (int i = 0; i < 4; ++i)
#pragma unroll
    for (int j = 0; j < 4; ++j) acc[i][j] = (f32x4)(0.f);

  for (int k0 = 0; k0 < K; k0 += 64) {
#pragma unroll
    for (int i = 0; i < 4; ++i) {
      int ch = (i * 4 + wave) * 64 + lane;
      int r = ch >> 3;
      int cg = (ch & 7) ^ (r & 7);
      int gr = min(m0 + r, M - 1);
      gload_lds16(&A[(size_t)gr * K + k0 + cg * 8], &sA[(size_t)(i * 4 + wave) * 512]);
      int gn = min(n0 + r, N - 1);
      gload_lds16(&B[(size_t)gn * K + k0 + cg * 8], &sB[(size_t)(i * 4 + wave) * 512]);
    }
    __syncthreads();
#pragma unroll
    for (int kk = 0; kk < 2; ++kk) {
      f16x8 af[4], bf[4];
      int cg = quad + kk * 4;
#pragma unroll
      for (int i = 0; i < 4; ++i) {
        int ra = wm + i * 16 + lrow;
        af[i] = *(const f16x8*)&sA[ra * 64 + ((cg ^ (ra & 7)) * 8)];
        int rb = wn + i * 16 + lrow;
        bf[i] = *(const f16x8*)&sB[rb * 64 + ((cg ^ (rb & 7)) * 8)];
      }
#pragma unroll
      for (int i = 0; i < 4; ++i)
#pragma unroll
        for (int j = 0; j < 4; ++j)
          acc[i][j] = __builtin_amdgcn_mfma_f32_16x16x32_f16(af[i], bf[j], acc[i][j], 0, 0, 0);
    }
    __syncthreads();
  }

  // epilogue: acc -> smem (f16 tile [128][128]) -> coalesced dwordx4 stores
  const int crow = quad * 4;
  const int ccol = lane & 15;
#pragma unroll
  for (int j = 0; j < 4; ++j) {
    int col = wn + j * 16 + ccol;
    int gcol = n0 + col;
    float bv = (gcol < N) ? bias[gcol] : 0.f;
#pragma unroll
    for (int i = 0; i < 4; ++i) {
#pragma unroll
      for (int r = 0; r < 4; ++r) {
        int row = wm + i * 16 + crow + r;
        smem[row * 128 + col] = (f16)fmaxf(acc[i][j][r] + bv, 0.f);
      }
    }
  }
  __syncthreads();
#pragma unroll
  for (int i = 0; i < 8; ++i) {
    int ch = i * 256 + (int)threadIdx.x;
    int r = ch >> 4;
    int cc = ch & 15;
    int grow = m0 + r;
    int gcol = n0 + cc * 8;
    if (grow < M && gcol < N)
      *(uint4*)&C[(size_t)grow * N + gcol] = *(const uint4*)&smem[r * 128 + cc * 8];
  }
}

// ---------- GEMM2: C = dinv ∘ (A[MxK] @ B[NxK]^T), fp16 out, tile 128x80 ----------
__global__ __launch_bounds__(256) void gemm2_f16(
    const f16* __restrict__ A, const f16* __restrict__ B,
    const float* __restrict__ dinv, f16* __restrict__ C,
    int M, int N, int K) {
  __shared__ __align__(16) f16 smem[128 * 64 + 80 * 64];  // 26 KB
  f16* sA = smem;
  f16* sB = smem + 128 * 64;

  const int mtc = (M + 127) >> 7;
  const int ntc = (N + 79) / 80;
  const int fullm = mtc & ~7;
  const int full = fullm * ntc;
  int idf = blockIdx.x;
  int mt, nt;
  if (idf < full) {
    int gsz = 8 * ntc;
    int grp = idf / gsz;
    int r = idf - grp * gsz;
    mt = grp * 8 + (r & 7);
    nt = r >> 3;
  } else {
    int r = idf - full;
    int rem = mtc - fullm;
    mt = fullm + r % rem;
    nt = r / rem;
  }
  const int m0 = mt * 128;
  const int n0 = nt * 80;
  const int lane = threadIdx.x & 63;
  const int wave = threadIdx.x >> 6;
  const int wm = wave * 32;
  const int lrow = lane & 15;
  const int quad = lane >> 4;

  f32x4 acc[2][5];
#pragma unroll
  for (int i = 0; i < 2; ++i)
#pragma unroll
    for (int j = 0; j < 5; ++j) acc[i][j] = (f32x4)(0.f);

  for (int k0 = 0; k0 < K; k0 += 64) {
#pragma unroll
    for (int i = 0; i < 4; ++i) {
      int ch = (i * 4 + wave) * 64 + lane;
      int r = ch >> 3;
      int cg = (ch & 7) ^ (r & 7);
      int gr = min(m0 + r, M - 1);
      gload_lds16(&A[(size_t)gr * K + k0 + cg * 8], &sA[(size_t)(i * 4 + wave) * 512]);
    }
#pragma unroll
    for (int i = 0; i < 3; ++i) {
      if (i * 4 + wave < 10) {  // 640 chunks, wave-uniform guard
        int ch = (i * 4 + wave) * 64 + lane;
        int r = ch >> 3;
        int cg = (ch & 7) ^ (r & 7);
        gload_lds16(&B[(size_t)(n0 + r) * K + k0 + cg * 8], &sB[(size_t)(i * 4 + wave) * 512]);
      }
    }
    __syncthreads();
#pragma unroll
    for (int kk = 0; kk < 2; ++kk) {
      f16x8 af[2], bf[5];
      int cg = quad + kk * 4;
#pragma unroll
      for (int i = 0; i < 2; ++i) {
        int ra = wm + i * 16 + lrow;
        af[i] = *(const f16x8*)&sA[ra * 64 + ((cg ^ (ra & 7)) * 8)];
      }
#pragma unroll
      for (int j = 0; j < 5; ++j) {
        int rb = j * 16 + lrow;
        bf[j] = *(const f16x8*)&sB[rb * 64 + ((cg ^ (rb & 7)) * 8)];
      }
#pragma unroll
      for (int i = 0; i < 2; ++i)
#pragma unroll
        for (int j = 0; j < 5; ++j)
          acc[i][j] = __builtin_amdgcn_mfma_f32_16x16x32_f16(af[i], bf[j], acc[i][j], 0, 0, 0);
    }
    __syncthreads();
  }

  // epilogue: scale rows by dinv, pack to smem, coalesced stores
  const int crow = quad * 4;
  const int ccol = lane & 15;
  float dsc[2][4];
#pragma unroll
  for (int i = 0; i < 2; ++i)
#pragma unroll
    for (int r = 0; r < 4; ++r) {
      int grow = m0 + wm + i * 16 + crow + r;
      dsc[i][r] = dinv[min(grow, M - 1)];
    }
#pragma unroll
  for (int j = 0; j < 5; ++j) {
    int col = j * 16 + ccol;
#pragma unroll
    for (int i = 0; i < 2; ++i) {
#pragma unroll
      for (int r = 0; r < 4; ++r) {
        int row = wm + i * 16 + crow + r;
        smem[row * 80 + col] = (f16)(acc[i][j][r] * dsc[i][r]);
      }
    }
  }
  __syncthreads();
#pragma unroll
  for (int i = 0; i < 5; ++i) {
    int ch = i * 256 + (int)threadIdx.x;  // of 1280 chunks (10 per row)
    int r = ch / 10;
    int rem = ch - 10 * r;
    int grow = m0 + r;
    if (grow < M)
      *(uint4*)&C[(size_t)grow * N + n0 + rem * 8] = *(const uint4*)&smem[r * 80 + rem * 8];
  }
}

extern "C" void kernel_launch(void* const* d_in, const int* in_sizes, int n_in,
                              void* d_out, int out_size, void* d_ws, size_t ws_size,
                              hipStream_t stream) {
  const float* x = (const float*)d_in[0];
  const void* edges = d_in[1];
  const float* W1 = (const float*)d_in[2];
  const float* b1 = (const float*)d_in[3];
  const float* W2 = (const float*)d_in[4];
  const float* b2 = (const float*)d_in[5];
  float* out = (float*)d_out;

  const int N1 = in_sizes[3];       // 1600
  const int N2 = in_sizes[5];       // 400
  const int K1 = in_sizes[2] / N1;  // 256
  const int K2 = in_sizes[4] / N2;  // 1600
  const int n = in_sizes[0] / K1;   // 20000
  const int E = in_sizes[1] / 2;    // 320000

  char* ws = (char*)d_ws;
  size_t o = 0;
  auto take = [&](size_t bytes) {
    char* p = ws + o;
    o += (bytes + 255) & ~(size_t)255;
    return p;
  };
  int* indeg = (int*)take((size_t)n * 4);
  int* cursor = (int*)take((size_t)n * 4);
  int* flag = (int*)take(4);
  size_t zero_bytes = o;
  int* rowptr = (int*)take((size_t)(n + 1) * 4);
  int* colsrc = (int*)take((size_t)E * 4);
  float* dinv = (float*)take((size_t)n * 4);
  f16* xs = (f16*)take((size_t)n * K1 * 2);    // 10 MB (dinv-premultiplied x)
  f16* xa = (f16*)take((size_t)n * K1 * 2);    // 10 MB
  f16* w1t = (f16*)take((size_t)K1 * N1 * 2);  // 0.8 MB
  f16* w2t = (f16*)take((size_t)K2 * N2 * 2);  // 1.3 MB
  f16* h = (f16*)take((size_t)n * N1 * 2);     // 64 MB
  f16* g = (f16*)take((size_t)n * N2 * 2);     // 16 MB (dinv-premultiplied)

  hipMemsetAsync(d_ws, 0, zero_bytes, stream);

  detect_kernel<<<1, 256, 0, stream>>>((const unsigned int*)edges, flag);
  deg_kernel<<<(E + 255) / 256, 256, 0, stream>>>(edges, flag, indeg, E);
  prefix_kernel<<<1, 1024, 0, stream>>>(indeg, rowptr, dinv, n);
  scatter_kernel<<<(E + 255) / 256, 256, 0, stream>>>(edges, flag, rowptr, cursor, colsrc, E);

  castT_kernel<<<(K1 * N1 + K2 * N2 + 255) / 256, 256, 0, stream>>>(W1, w1t, K1, N1, W2, w2t,
                                                                    K2, N2);
  xcast_kernel<<<(n * 64 + 255) / 256, 256, 0, stream>>>(x, dinv, xs, n);

  // Layer 1: aggregate at 256 dims (fp16), GEMM (+b1, relu, fp16 out)
  agg1_kernel<<<(n + 3) / 4, 256, 0, stream>>>(xs, dinv, rowptr, colsrc, xa, n);
  {
    dim3 grid((N1 + 127) / 128, (n + 127) / 128);
    gemm1_f16<<<grid, 256, 0, stream>>>(xa, w1t, b1, h, n, N1, K1);
  }
  // Layer 2: GEMM (dinv-scaled fp16 out), then aggregate (+b2, fp32 out)
  {
    int mtc = (n + 127) / 128;
    int ntc = (N2 + 79) / 80;
    gemm2_f16<<<mtc * ntc, 256, 0, stream>>>(h, w2t, dinv, g, n, N2, K2);
  }
  agg2_kernel<<<(n + 3) / 4, 256, 0, stream>>>(g, dinv, rowptr, colsrc, b2, out, n, N2);
}

// Round 7
// 279.573 us; speedup vs baseline: 1.3357x; 1.0443x over previous
//
#include <hip/hip_runtime.h>
#include <hip/hip_bf16.h>
#include <stdint.h>

typedef _Float16 f16;
typedef _Float16 f16x8 __attribute__((ext_vector_type(8)));
typedef _Float16 f16v4 __attribute__((ext_vector_type(4)));
typedef float f32x4 __attribute__((ext_vector_type(4)));

// async 16B global->LDS (wave-uniform LDS base + lane*16)
__device__ __forceinline__ void gload_lds16(const f16* g, f16* l) {
  __builtin_amdgcn_global_load_lds(
      (const __attribute__((address_space(1))) void*)g,
      (__attribute__((address_space(3))) void*)l, 16, 0, 0);
}

// ---------- edge access: handles int32 or int64 storage of edge_index ----------
__device__ __forceinline__ int edge_at(const void* ep, int isI64, long long idx) {
  if (isI64) return (int)((const long long*)ep)[idx];
  return ((const int*)ep)[idx];
}

__global__ void detect_kernel(const unsigned int* __restrict__ e, int* __restrict__ flag) {
  __shared__ int any;
  if (threadIdx.x == 0) any = 0;
  __syncthreads();
  for (int idx = 1 + 2 * (int)threadIdx.x; idx < 4096; idx += 512) {
    if (e[idx] != 0u) any = 1;
  }
  __syncthreads();
  if (threadIdx.x == 0) flag[0] = any ? 0 : 1;
}

__global__ void deg_kernel(const void* __restrict__ ep, const int* __restrict__ flag,
                           int* __restrict__ indeg, int E) {
  int e = blockIdx.x * blockDim.x + threadIdx.x;
  if (e >= E) return;
  int i64 = flag[0];
  int d = edge_at(ep, i64, (long long)E + e);
  atomicAdd(&indeg[d], 1);
}

// ---------- parallel scan stage 1: per-block sum (+dinv) ----------
__global__ __launch_bounds__(1024) void scan1_kernel(const int* __restrict__ indeg,
                                                     float* __restrict__ dinv,
                                                     int* __restrict__ bsum, int n) {
  __shared__ int ws[16];
  int t = threadIdx.x;
  int i = blockIdx.x * 1024 + t;
  int v = (i < n) ? indeg[i] : 0;
  if (i < n) dinv[i] = rsqrtf((float)(v + 1));
  int s = v;
#pragma unroll
  for (int off = 32; off > 0; off >>= 1) s += __shfl_down(s, off, 64);
  if ((t & 63) == 0) ws[t >> 6] = s;
  __syncthreads();
  if (t < 16) {
    int x = ws[t];
#pragma unroll
    for (int off = 8; off > 0; off >>= 1) x += __shfl_down(x, off, 64);
    if (t == 0) bsum[blockIdx.x] = x;
  }
}

// ---------- stage 2: exclusive scan of block sums (nb <= 64) ----------
__global__ void scan2_kernel(const int* __restrict__ bsum, int* __restrict__ boff, int nb) {
  int lane = threadIdx.x;
  int v = (lane < nb) ? bsum[lane] : 0;
  int sv = v;
#pragma unroll
  for (int off = 1; off < 64; off <<= 1) {
    int u = __shfl_up(sv, off, 64);
    if (lane >= off) sv += u;
  }
  if (lane < nb) boff[lane] = sv - v;
}

// ---------- stage 3: local inclusive scan + block offset -> rowptr ----------
__global__ __launch_bounds__(1024) void scan3_kernel(const int* __restrict__ indeg,
                                                     const int* __restrict__ boff,
                                                     int* __restrict__ rowptr, int n) {
  __shared__ int wsum[16];
  int t = threadIdx.x;
  int lane = t & 63;
  int w = t >> 6;
  int i = blockIdx.x * 1024 + t;
  int v = (i < n) ? indeg[i] : 0;
  int sv = v;
#pragma unroll
  for (int off = 1; off < 64; off <<= 1) {
    int u = __shfl_up(sv, off, 64);
    if (lane >= off) sv += u;
  }
  if (lane == 63) wsum[w] = sv;
  __syncthreads();
  if (w == 0 && lane < 16) {
    int x = wsum[lane];
#pragma unroll
    for (int off = 1; off < 16; off <<= 1) {
      int u = __shfl_up(x, off, 64);
      if (lane >= off) x += u;
    }
    wsum[lane] = x;
  }
  __syncthreads();
  int woff = (w > 0) ? wsum[w - 1] : 0;
  if (i < n) rowptr[i + 1] = boff[blockIdx.x] + woff + sv;
  if (i == 0) rowptr[0] = 0;
}

__global__ void scatter_kernel(const void* __restrict__ ep, const int* __restrict__ flag,
                               const int* __restrict__ rowptr, int* __restrict__ cursor,
                               int* __restrict__ colsrc, int E) {
  int e = blockIdx.x * blockDim.x + threadIdx.x;
  if (e >= E) return;
  int i64 = flag[0];
  int s = edge_at(ep, i64, (long long)e);
  int d = edge_at(ep, i64, (long long)E + e);
  int pos = atomicAdd(&cursor[d], 1);
  colsrc[rowptr[d] + pos] = s;
}

// ---------- xs = (f16)(dinv[row] * x): 4 floats per thread ----------
__global__ void xcast_kernel(const float* __restrict__ x, const float* __restrict__ dinv,
                             f16* __restrict__ xs, int n) {
  int c = blockIdx.x * 256 + threadIdx.x;  // chunk of 4 elems; 64 chunks/row
  if (c >= n * 64) return;
  int row = c >> 6;
  float d = dinv[row];
  float4 v = ((const float4*)x)[c];
  f16v4 r;
  r[0] = (f16)(d * v.x);
  r[1] = (f16)(d * v.y);
  r[2] = (f16)(d * v.z);
  r[3] = (f16)(d * v.w);
  ((f16v4*)xs)[c] = r;
}

// ---------- agg1: wave per node over fp16 xs (dinv-premultiplied), 4-way unrolled ----------
__global__ __launch_bounds__(256) void agg1_kernel(const f16* __restrict__ xs,
                                                   const float* __restrict__ dinv,
                                                   const int* __restrict__ rowptr,
                                                   const int* __restrict__ colsrc,
                                                   f16* __restrict__ xa, int n) {
  int wave = threadIdx.x >> 6;
  int lane = threadIdx.x & 63;
  int i = blockIdx.x * 4 + wave;
  if (i >= n) return;
  const f16v4* xp = (const f16v4*)xs;  // row = 64 f16v4 chunks
  float di = dinv[i];
  f16v4 s = xp[(size_t)i * 64 + lane];
  float a0 = (float)s[0], a1 = (float)s[1], a2 = (float)s[2], a3 = (float)s[3];
  float b0 = 0.f, b1 = 0.f, b2 = 0.f, b3 = 0.f;
  int beg = rowptr[i], end = rowptr[i + 1];
  int j = beg;
  for (; j + 3 < end; j += 4) {
    int s0 = colsrc[j], s1 = colsrc[j + 1], s2 = colsrc[j + 2], s3 = colsrc[j + 3];
    f16v4 v0 = xp[(size_t)s0 * 64 + lane];
    f16v4 v1 = xp[(size_t)s1 * 64 + lane];
    f16v4 v2 = xp[(size_t)s2 * 64 + lane];
    f16v4 v3 = xp[(size_t)s3 * 64 + lane];
    a0 += (float)v0[0] + (float)v2[0]; a1 += (float)v0[1] + (float)v2[1];
    a2 += (float)v0[2] + (float)v2[2]; a3 += (float)v0[3] + (float)v2[3];
    b0 += (float)v1[0] + (float)v3[0]; b1 += (float)v1[1] + (float)v3[1];
    b2 += (float)v1[2] + (float)v3[2]; b3 += (float)v1[3] + (float)v3[3];
  }
  for (; j < end; ++j) {
    int s0 = colsrc[j];
    f16v4 v0 = xp[(size_t)s0 * 64 + lane];
    a0 += (float)v0[0]; a1 += (float)v0[1]; a2 += (float)v0[2]; a3 += (float)v0[3];
  }
  f16v4 r;
  r[0] = (f16)(di * (a0 + b0));
  r[1] = (f16)(di * (a1 + b1));
  r[2] = (f16)(di * (a2 + b2));
  r[3] = (f16)(di * (a3 + b3));
  *(f16v4*)&xa[(size_t)i * 256 + lane * 4] = r;
}

// ---------- agg2: wave per node over dinv-premultiplied gs, 4-way unrolled ----------
__global__ __launch_bounds__(256) void agg2_kernel(const f16* __restrict__ gs,
                                                   const float* __restrict__ dinv,
                                                   const int* __restrict__ rowptr,
                                                   const int* __restrict__ colsrc,
                                                   const float* __restrict__ bias,
                                                   float* __restrict__ out, int n, int F) {
  int wave = threadIdx.x >> 6;
  int lane = threadIdx.x & 63;
  int i = blockIdx.x * 4 + wave;
  if (i >= n) return;
  int base = lane * 8;
  if (base >= F) return;
  float di = dinv[i];
  f16x8 sv = *(const f16x8*)&gs[(size_t)i * F + base];
  float a[8], b[8];
#pragma unroll
  for (int r = 0; r < 8; ++r) { a[r] = (float)sv[r]; b[r] = 0.f; }
  int beg = rowptr[i], end = rowptr[i + 1];
  int j = beg;
  for (; j + 3 < end; j += 4) {
    int s0 = colsrc[j], s1 = colsrc[j + 1], s2 = colsrc[j + 2], s3 = colsrc[j + 3];
    f16x8 v0 = *(const f16x8*)&gs[(size_t)s0 * F + base];
    f16x8 v1 = *(const f16x8*)&gs[(size_t)s1 * F + base];
    f16x8 v2 = *(const f16x8*)&gs[(size_t)s2 * F + base];
    f16x8 v3 = *(const f16x8*)&gs[(size_t)s3 * F + base];
#pragma unroll
    for (int r = 0; r < 8; ++r) {
      a[r] += (float)v0[r] + (float)v2[r];
      b[r] += (float)v1[r] + (float)v3[r];
    }
  }
  for (; j < end; ++j) {
    int s0 = colsrc[j];
    f16x8 v0 = *(const f16x8*)&gs[(size_t)s0 * F + base];
#pragma unroll
    for (int r = 0; r < 8; ++r) a[r] += (float)v0[r];
  }
  float4 o0, o1;
  float4 bv0 = *(const float4*)&bias[base];
  float4 bv1 = *(const float4*)&bias[base + 4];
  o0.x = di * (a[0] + b[0]) + bv0.x; o0.y = di * (a[1] + b[1]) + bv0.y;
  o0.z = di * (a[2] + b[2]) + bv0.z; o0.w = di * (a[3] + b[3]) + bv0.w;
  o1.x = di * (a[4] + b[4]) + bv1.x; o1.y = di * (a[5] + b[5]) + bv1.y;
  o1.z = di * (a[6] + b[6]) + bv1.z; o1.w = di * (a[7] + b[7]) + bv1.w;
  *(float4*)&out[(size_t)i * F + base] = o0;
  *(float4*)&out[(size_t)i * F + base + 4] = o1;
}

// ---------- both weight casts in one launch: W[K][N] -> Wt[N][K] fp16 ----------
__global__ void castT_kernel(const float* __restrict__ W1, f16* __restrict__ W1t, int K1, int N1,
                             const float* __restrict__ W2, f16* __restrict__ W2t, int K2, int N2) {
  int idx = blockIdx.x * 256 + threadIdx.x;
  int t1 = K1 * N1;
  if (idx < t1) {
    int k = idx / N1;
    int nn = idx - k * N1;
    W1t[(size_t)nn * K1 + k] = (f16)W1[idx];
  } else {
    idx -= t1;
    if (idx < K2 * N2) {
      int k = idx / N2;
      int nn = idx - k * N2;
      W2t[(size_t)nn * K2 + k] = (f16)W2[idx];
    }
  }
}

// ---------- GEMM1: C = A[MxK] @ B[NxK]^T, +bias +relu, fp16 out ----------
// 128x128 tile, BK=64, async global_load_lds staging w/ XOR chunk swizzle,
// LDS-repacked coalesced epilogue.
__global__ __launch_bounds__(256) void gemm1_f16(
    const f16* __restrict__ A, const f16* __restrict__ B,
    const float* __restrict__ bias, f16* __restrict__ C,
    int M, int N, int K) {
  __shared__ __align__(16) f16 smem[2 * 128 * 64];  // 32 KB: sA | sB, also epilogue buffer
  f16* sA = smem;
  f16* sB = smem + 128 * 64;
  const int m0 = blockIdx.y * 128;
  const int n0 = blockIdx.x * 128;
  const int lane = threadIdx.x & 63;
  const int wave = threadIdx.x >> 6;
  const int wm = (wave & 1) * 64;
  const int wn = (wave >> 1) * 64;
  const int lrow = lane & 15;
  const int quad = lane >> 4;

  f32x4 acc[4][4];
#pragma unroll
  for (int i = 0; i < 4; ++i)
#pragma unroll
    for (int j = 0; j < 4; ++j) acc[i][j] = (f32x4)(0.f);

  for (int k0 = 0; k0 < K; k0 += 64) {
#pragma unroll
    for (int i = 0; i < 4; ++i) {
      int ch = (i * 4 + wave) * 64 + lane;
      int r = ch >> 3;
      int cg = (ch & 7) ^ (r & 7);
      int gr = min(m0 + r, M - 1);
      gload_lds16(&A[(size_t)gr * K + k0 + cg * 8], &sA[(size_t)(i * 4 + wave) * 512]);
      int gn = min(n0 + r, N - 1);
      gload_lds16(&B[(size_t)gn * K + k0 + cg * 8], &sB[(size_t)(i * 4 + wave) * 512]);
    }
    __syncthreads();
#pragma unroll
    for (int kk = 0; kk < 2; ++kk) {
      f16x8 af[4], bf[4];
      int cg = quad + kk * 4;
#pragma unroll
      for (int i = 0; i < 4; ++i) {
        int ra = wm + i * 16 + lrow;
        af[i] = *(const f16x8*)&sA[ra * 64 + ((cg ^ (ra & 7)) * 8)];
        int rb = wn + i * 16 + lrow;
        bf[i] = *(const f16x8*)&sB[rb * 64 + ((cg ^ (rb & 7)) * 8)];
      }
#pragma unroll
      for (int i = 0; i < 4; ++i)
#pragma unroll
        for (int j = 0; j < 4; ++j)
          acc[i][j] = __builtin_amdgcn_mfma_f32_16x16x32_f16(af[i], bf[j], acc[i][j], 0, 0, 0);
    }
    __syncthreads();
  }

  // epilogue: acc -> smem (f16 tile [128][128]) -> coalesced dwordx4 stores
  const int crow = quad * 4;
  const int ccol = lane & 15;
#pragma unroll
  for (int j = 0; j < 4; ++j) {
    int col = wn + j * 16 + ccol;
    int gcol = n0 + col;
    float bv = (gcol < N) ? bias[gcol] : 0.f;
#pragma unroll
    for (int i = 0; i < 4; ++i) {
#pragma unroll
      for (int r = 0; r < 4; ++r) {
        int row = wm + i * 16 + crow + r;
        smem[row * 128 + col] = (f16)fmaxf(acc[i][j][r] + bv, 0.f);
      }
    }
  }
  __syncthreads();
#pragma unroll
  for (int i = 0; i < 8; ++i) {
    int ch = i * 256 + (int)threadIdx.x;
    int r = ch >> 4;
    int cc = ch & 15;
    int grow = m0 + r;
    int gcol = n0 + cc * 8;
    if (grow < M && gcol < N)
      *(uint4*)&C[(size_t)grow * N + gcol] = *(const uint4*)&smem[r * 128 + cc * 8];
  }
}

// ---------- GEMM2: C = dinv ∘ (A[MxK] @ B[NxK]^T), fp16 out, tile 64x80 ----------
// Small tile -> 1565 blocks (~6/CU) to hide the 2-barrier K-loop latency.
__global__ __launch_bounds__(256) void gemm2_f16(
    const f16* __restrict__ A, const f16* __restrict__ B,
    const float* __restrict__ dinv, f16* __restrict__ C,
    int M, int N, int K) {
  __shared__ __align__(16) f16 smem[64 * 64 + 80 * 64];  // 18 KB
  f16* sA = smem;
  f16* sB = smem + 64 * 64;

  const int mtc = (M + 63) >> 6;
  const int ntc = (N + 79) / 80;
  const int fullm = mtc & ~7;
  const int full = fullm * ntc;
  int idf = blockIdx.x;
  int mt, nt;
  if (idf < full) {
    int gsz = 8 * ntc;
    int grp = idf / gsz;
    int r = idf - grp * gsz;
    mt = grp * 8 + (r & 7);
    nt = r >> 3;
  } else {
    int r = idf - full;
    int rem = mtc - fullm;
    mt = fullm + r % rem;
    nt = r / rem;
  }
  const int m0 = mt * 64;
  const int n0 = nt * 80;
  const int lane = threadIdx.x & 63;
  const int wave = threadIdx.x >> 6;
  const int lrow = lane & 15;
  const int quad = lane >> 4;

  f32x4 acc[5];
#pragma unroll
  for (int j = 0; j < 5; ++j) acc[j] = (f32x4)(0.f);

  for (int k0 = 0; k0 < K; k0 += 64) {
    // sA: 64x64 = 512 chunks (slots 0..7), 2 per thread
#pragma unroll
    for (int i = 0; i < 2; ++i) {
      int ch = (i * 4 + wave) * 64 + lane;
      int r = ch >> 3;
      int cg = (ch & 7) ^ (r & 7);
      int gr = min(m0 + r, M - 1);
      gload_lds16(&A[(size_t)gr * K + k0 + cg * 8], &sA[(size_t)(i * 4 + wave) * 512]);
    }
    // sB: 80x64 = 640 chunks (slots 0..9), wave-uniform guard
#pragma unroll
    for (int i = 0; i < 3; ++i) {
      if (i * 4 + wave < 10) {
        int ch = (i * 4 + wave) * 64 + lane;
        int r = ch >> 3;
        int cg = (ch & 7) ^ (r & 7);
        int gn = min(n0 + r, N - 1);
        gload_lds16(&B[(size_t)gn * K + k0 + cg * 8], &sB[(size_t)(i * 4 + wave) * 512]);
      }
    }
    __syncthreads();
#pragma unroll
    for (int kk = 0; kk < 2; ++kk) {
      int cg = quad + kk * 4;
      int ra = wave * 16 + lrow;
      f16x8 af = *(const f16x8*)&sA[ra * 64 + ((cg ^ (ra & 7)) * 8)];
      f16x8 bf[5];
#pragma unroll
      for (int j = 0; j < 5; ++j) {
        int rb = j * 16 + lrow;
        bf[j] = *(const f16x8*)&sB[rb * 64 + ((cg ^ (rb & 7)) * 8)];
      }
#pragma unroll
      for (int j = 0; j < 5; ++j)
        acc[j] = __builtin_amdgcn_mfma_f32_16x16x32_f16(af, bf[j], acc[j], 0, 0, 0);
    }
    __syncthreads();
  }

  // epilogue: scale rows by dinv, pack to smem [64][80], coalesced stores
  const int crow = quad * 4;
  const int ccol = lane & 15;
  float dsc[4];
#pragma unroll
  for (int r = 0; r < 4; ++r) {
    int grow = m0 + wave * 16 + crow + r;
    dsc[r] = dinv[min(grow, M - 1)];
  }
#pragma unroll
  for (int j = 0; j < 5; ++j) {
    int col = j * 16 + ccol;
#pragma unroll
    for (int r = 0; r < 4; ++r) {
      int row = wave * 16 + crow + r;
      smem[row * 80 + col] = (f16)(acc[j][r] * dsc[r]);
    }
  }
  __syncthreads();
#pragma unroll
  for (int i = 0; i < 3; ++i) {
    int ch = i * 256 + (int)threadIdx.x;  // of 640 chunks (10 per row)
    if (ch < 640) {
      int r = ch / 10;
      int rem = ch - 10 * r;
      int grow = m0 + r;
      if (grow < M)
        *(uint4*)&C[(size_t)grow * N + n0 + rem * 8] = *(const uint4*)&smem[r * 80 + rem * 8];
    }
  }
}

extern "C" void kernel_launch(void* const* d_in, const int* in_sizes, int n_in,
                              void* d_out, int out_size, void* d_ws, size_t ws_size,
                              hipStream_t stream) {
  const float* x = (const float*)d_in[0];
  const void* edges = d_in[1];
  const float* W1 = (const float*)d_in[2];
  const float* b1 = (const float*)d_in[3];
  const float* W2 = (const float*)d_in[4];
  const float* b2 = (const float*)d_in[5];
  float* out = (float*)d_out;

  const int N1 = in_sizes[3];       // 1600
  const int N2 = in_sizes[5];       // 400
  const int K1 = in_sizes[2] / N1;  // 256
  const int K2 = in_sizes[4] / N2;  // 1600
  const int n = in_sizes[0] / K1;   // 20000
  const int E = in_sizes[1] / 2;    // 320000

  char* ws = (char*)d_ws;
  size_t o = 0;
  auto take = [&](size_t bytes) {
    char* p = ws + o;
    o += (bytes + 255) & ~(size_t)255;
    return p;
  };
  int* indeg = (int*)take((size_t)n * 4);
  int* cursor = (int*)take((size_t)n * 4);
  int* flag = (int*)take(4);
  size_t zero_bytes = o;
  int* rowptr = (int*)take((size_t)(n + 1) * 4);
  int* colsrc = (int*)take((size_t)E * 4);
  float* dinv = (float*)take((size_t)n * 4);
  int* bsum = (int*)take(64 * 4);
  int* boff = (int*)take(64 * 4);
  f16* xs = (f16*)take((size_t)n * K1 * 2);    // 10 MB (dinv-premultiplied x)
  f16* xa = (f16*)take((size_t)n * K1 * 2);    // 10 MB
  f16* w1t = (f16*)take((size_t)K1 * N1 * 2);  // 0.8 MB
  f16* w2t = (f16*)take((size_t)K2 * N2 * 2);  // 1.3 MB
  f16* h = (f16*)take((size_t)n * N1 * 2);     // 64 MB
  f16* g = (f16*)take((size_t)n * N2 * 2);     // 16 MB (dinv-premultiplied)

  hipMemsetAsync(d_ws, 0, zero_bytes, stream);

  const int nb = (n + 1023) / 1024;  // 20 <= 64

  detect_kernel<<<1, 256, 0, stream>>>((const unsigned int*)edges, flag);
  deg_kernel<<<(E + 255) / 256, 256, 0, stream>>>(edges, flag, indeg, E);
  scan1_kernel<<<nb, 1024, 0, stream>>>(indeg, dinv, bsum, n);
  scan2_kernel<<<1, 64, 0, stream>>>(bsum, boff, nb);
  scan3_kernel<<<nb, 1024, 0, stream>>>(indeg, boff, rowptr, n);
  scatter_kernel<<<(E + 255) / 256, 256, 0, stream>>>(edges, flag, rowptr, cursor, colsrc, E);

  castT_kernel<<<(K1 * N1 + K2 * N2 + 255) / 256, 256, 0, stream>>>(W1, w1t, K1, N1, W2, w2t,
                                                                    K2, N2);
  xcast_kernel<<<(n * 64 + 255) / 256, 256, 0, stream>>>(x, dinv, xs, n);

  // Layer 1: aggregate at 256 dims (fp16), GEMM (+b1, relu, fp16 out)
  agg1_kernel<<<(n + 3) / 4, 256, 0, stream>>>(xs, dinv, rowptr, colsrc, xa, n);
  {
    dim3 grid((N1 + 127) / 128, (n + 127) / 128);
    gemm1_f16<<<grid, 256, 0, stream>>>(xa, w1t, b1, h, n, N1, K1);
  }
  // Layer 2: GEMM (dinv-scaled fp16 out, 64x80 tiles), then aggregate (+b2, fp32 out)
  {
    int mtc = (n + 63) / 64;
    int ntc = (N2 + 79) / 80;
    gemm2_f16<<<mtc * ntc, 256, 0, stream>>>(h, w2t, dinv, g, n, N2, K2);
  }
  agg2_kernel<<<(n + 3) / 4, 256, 0, stream>>>(g, dinv, rowptr, colsrc, b2, out, n, N2);
}

// Round 8
// 264.903 us; speedup vs baseline: 1.4097x; 1.0554x over previous
//
#include <hip/hip_runtime.h>
#include <hip/hip_bf16.h>
#include <stdint.h>

typedef _Float16 f16;
typedef _Float16 f16x8 __attribute__((ext_vector_type(8)));
typedef _Float16 f16v4 __attribute__((ext_vector_type(4)));
typedef float f32x4 __attribute__((ext_vector_type(4)));

// async 16B global->LDS (wave-uniform LDS base + lane*16)
__device__ __forceinline__ void gload_lds16(const f16* g, f16* l) {
  __builtin_amdgcn_global_load_lds(
      (const __attribute__((address_space(1))) void*)g,
      (__attribute__((address_space(3))) void*)l, 16, 0, 0);
}

// ---------- edge access: handles int32 or int64 storage of edge_index ----------
__device__ __forceinline__ int edge_at(const void* ep, int isI64, long long idx) {
  if (isI64) return (int)((const long long*)ep)[idx];
  return ((const int*)ep)[idx];
}

// ---------- block 0: int64 detect; blocks >=1: weight cast+transpose ----------
__global__ void detect_castT_kernel(const unsigned int* __restrict__ e, int* __restrict__ flag,
                                    const float* __restrict__ W1, f16* __restrict__ W1t,
                                    int K1, int N1,
                                    const float* __restrict__ W2, f16* __restrict__ W2t,
                                    int K2, int N2) {
  if (blockIdx.x == 0) {
    __shared__ int any;
    if (threadIdx.x == 0) any = 0;
    __syncthreads();
    for (int idx = 1 + 2 * (int)threadIdx.x; idx < 4096; idx += 512) {
      if (e[idx] != 0u) any = 1;
    }
    __syncthreads();
    if (threadIdx.x == 0) flag[0] = any ? 0 : 1;
    return;
  }
  int idx = (blockIdx.x - 1) * 256 + threadIdx.x;
  int t1 = K1 * N1;
  if (idx < t1) {
    int k = idx / N1;
    int nn = idx - k * N1;
    W1t[(size_t)nn * K1 + k] = (f16)W1[idx];
  } else {
    idx -= t1;
    if (idx < K2 * N2) {
      int k = idx / N2;
      int nn = idx - k * N2;
      W2t[(size_t)nn * K2 + k] = (f16)W2[idx];
    }
  }
}

__global__ void deg_kernel(const void* __restrict__ ep, const int* __restrict__ flag,
                           int* __restrict__ indeg, int E) {
  int e = blockIdx.x * blockDim.x + threadIdx.x;
  if (e >= E) return;
  int i64 = flag[0];
  int d = edge_at(ep, i64, (long long)E + e);
  atomicAdd(&indeg[d], 1);
}

// ---------- scan stage 1: per-block sum (+dinv) ----------
__global__ __launch_bounds__(1024) void scan1_kernel(const int* __restrict__ indeg,
                                                     float* __restrict__ dinv,
                                                     int* __restrict__ bsum, int n) {
  __shared__ int ws[16];
  int t = threadIdx.x;
  int i = blockIdx.x * 1024 + t;
  int v = (i < n) ? indeg[i] : 0;
  if (i < n) dinv[i] = rsqrtf((float)(v + 1));
  int s = v;
#pragma unroll
  for (int off = 32; off > 0; off >>= 1) s += __shfl_down(s, off, 64);
  if ((t & 63) == 0) ws[t >> 6] = s;
  __syncthreads();
  if (t < 16) {
    int x = ws[t];
#pragma unroll
    for (int off = 8; off > 0; off >>= 1) x += __shfl_down(x, off, 64);
    if (t == 0) bsum[blockIdx.x] = x;
  }
}

// ---------- scan stage 2: local scan + redundant block-sum scan -> rowptr ----------
__global__ __launch_bounds__(1024) void scan3_kernel(const int* __restrict__ indeg,
                                                     const int* __restrict__ bsum,
                                                     int* __restrict__ rowptr, int n, int nb) {
  __shared__ int wsum[16];
  __shared__ int bexcl[64];
  int t = threadIdx.x;
  int lane = t & 63;
  int w = t >> 6;
  int i = blockIdx.x * 1024 + t;
  int v = (i < n) ? indeg[i] : 0;
  int sv = v;
#pragma unroll
  for (int off = 1; off < 64; off <<= 1) {
    int u = __shfl_up(sv, off, 64);
    if (lane >= off) sv += u;
  }
  if (lane == 63) wsum[w] = sv;
  __syncthreads();
  if (w == 0) {
    // scan the 16 wave sums
    if (lane < 16) {
      int x = wsum[lane];
#pragma unroll
      for (int off = 1; off < 16; off <<= 1) {
        int u = __shfl_up(x, off, 64);
        if (lane >= off) x += u;
      }
      wsum[lane] = x;
    }
    // redundant exclusive scan of block sums (nb <= 64)
    int bv = (lane < nb) ? bsum[lane] : 0;
    int bs = bv;
#pragma unroll
    for (int off = 1; off < 64; off <<= 1) {
      int u = __shfl_up(bs, off, 64);
      if (lane >= off) bs += u;
    }
    bexcl[lane] = bs - bv;
  }
  __syncthreads();
  int woff = (w > 0) ? wsum[w - 1] : 0;
  if (i < n) rowptr[i + 1] = bexcl[blockIdx.x] + woff + sv;
  if (i == 0) rowptr[0] = 0;
}

// ---------- blocks < sb: scatter edges to CSR; rest: xs = (f16)(dinv*x) ----------
__global__ void scatter_xcast_kernel(const void* __restrict__ ep, const int* __restrict__ flag,
                                     const int* __restrict__ rowptr, int* __restrict__ cursor,
                                     int* __restrict__ colsrc, int E, int sb,
                                     const float* __restrict__ x, const float* __restrict__ dinv,
                                     f16* __restrict__ xs, int n) {
  int b = blockIdx.x;
  if (b < sb) {
    int e = b * 256 + threadIdx.x;
    if (e >= E) return;
    int i64 = flag[0];
    int s = edge_at(ep, i64, (long long)e);
    int d = edge_at(ep, i64, (long long)E + e);
    int pos = atomicAdd(&cursor[d], 1);
    colsrc[rowptr[d] + pos] = s;
    return;
  }
  int c = (b - sb) * 256 + threadIdx.x;  // chunk of 4 floats; 64 chunks/row
  if (c >= n * 64) return;
  int row = c >> 6;
  float d = dinv[row];
  float4 v = ((const float4*)x)[c];
  f16v4 r;
  r[0] = (f16)(d * v.x);
  r[1] = (f16)(d * v.y);
  r[2] = (f16)(d * v.z);
  r[3] = (f16)(d * v.w);
  ((f16v4*)xs)[c] = r;
}

// ---------- agg1: wave per node over fp16 xs (dinv-premultiplied), 4-way unrolled ----------
__global__ __launch_bounds__(256) void agg1_kernel(const f16* __restrict__ xs,
                                                   const float* __restrict__ dinv,
                                                   const int* __restrict__ rowptr,
                                                   const int* __restrict__ colsrc,
                                                   f16* __restrict__ xa, int n) {
  int wave = threadIdx.x >> 6;
  int lane = threadIdx.x & 63;
  int i = blockIdx.x * 4 + wave;
  if (i >= n) return;
  const f16v4* xp = (const f16v4*)xs;  // row = 64 f16v4 chunks
  float di = dinv[i];
  f16v4 s = xp[(size_t)i * 64 + lane];
  float a0 = (float)s[0], a1 = (float)s[1], a2 = (float)s[2], a3 = (float)s[3];
  float b0 = 0.f, b1 = 0.f, b2 = 0.f, b3 = 0.f;
  int beg = rowptr[i], end = rowptr[i + 1];
  int j = beg;
  for (; j + 3 < end; j += 4) {
    int s0 = colsrc[j], s1 = colsrc[j + 1], s2 = colsrc[j + 2], s3 = colsrc[j + 3];
    f16v4 v0 = xp[(size_t)s0 * 64 + lane];
    f16v4 v1 = xp[(size_t)s1 * 64 + lane];
    f16v4 v2 = xp[(size_t)s2 * 64 + lane];
    f16v4 v3 = xp[(size_t)s3 * 64 + lane];
    a0 += (float)v0[0] + (float)v2[0]; a1 += (float)v0[1] + (float)v2[1];
    a2 += (float)v0[2] + (float)v2[2]; a3 += (float)v0[3] + (float)v2[3];
    b0 += (float)v1[0] + (float)v3[0]; b1 += (float)v1[1] + (float)v3[1];
    b2 += (float)v1[2] + (float)v3[2]; b3 += (float)v1[3] + (float)v3[3];
  }
  for (; j < end; ++j) {
    int s0 = colsrc[j];
    f16v4 v0 = xp[(size_t)s0 * 64 + lane];
    a0 += (float)v0[0]; a1 += (float)v0[1]; a2 += (float)v0[2]; a3 += (float)v0[3];
  }
  f16v4 r;
  r[0] = (f16)(di * (a0 + b0));
  r[1] = (f16)(di * (a1 + b1));
  r[2] = (f16)(di * (a2 + b2));
  r[3] = (f16)(di * (a3 + b3));
  *(f16v4*)&xa[(size_t)i * 256 + lane * 4] = r;
}

// ---------- agg2: wave per node over dinv-premultiplied gs, 4-way unrolled ----------
__global__ __launch_bounds__(256) void agg2_kernel(const f16* __restrict__ gs,
                                                   const float* __restrict__ dinv,
                                                   const int* __restrict__ rowptr,
                                                   const int* __restrict__ colsrc,
                                                   const float* __restrict__ bias,
                                                   float* __restrict__ out, int n, int F) {
  int wave = threadIdx.x >> 6;
  int lane = threadIdx.x & 63;
  int i = blockIdx.x * 4 + wave;
  if (i >= n) return;
  int base = lane * 8;
  if (base >= F) return;
  float di = dinv[i];
  f16x8 sv = *(const f16x8*)&gs[(size_t)i * F + base];
  float a[8], b[8];
#pragma unroll
  for (int r = 0; r < 8; ++r) { a[r] = (float)sv[r]; b[r] = 0.f; }
  int beg = rowptr[i], end = rowptr[i + 1];
  int j = beg;
  for (; j + 3 < end; j += 4) {
    int s0 = colsrc[j], s1 = colsrc[j + 1], s2 = colsrc[j + 2], s3 = colsrc[j + 3];
    f16x8 v0 = *(const f16x8*)&gs[(size_t)s0 * F + base];
    f16x8 v1 = *(const f16x8*)&gs[(size_t)s1 * F + base];
    f16x8 v2 = *(const f16x8*)&gs[(size_t)s2 * F + base];
    f16x8 v3 = *(const f16x8*)&gs[(size_t)s3 * F + base];
#pragma unroll
    for (int r = 0; r < 8; ++r) {
      a[r] += (float)v0[r] + (float)v2[r];
      b[r] += (float)v1[r] + (float)v3[r];
    }
  }
  for (; j < end; ++j) {
    int s0 = colsrc[j];
    f16x8 v0 = *(const f16x8*)&gs[(size_t)s0 * F + base];
#pragma unroll
    for (int r = 0; r < 8; ++r) a[r] += (float)v0[r];
  }
  float4 o0, o1;
  float4 bv0 = *(const float4*)&bias[base];
  float4 bv1 = *(const float4*)&bias[base + 4];
  o0.x = di * (a[0] + b[0]) + bv0.x; o0.y = di * (a[1] + b[1]) + bv0.y;
  o0.z = di * (a[2] + b[2]) + bv0.z; o0.w = di * (a[3] + b[3]) + bv0.w;
  o1.x = di * (a[4] + b[4]) + bv1.x; o1.y = di * (a[5] + b[5]) + bv1.y;
  o1.z = di * (a[6] + b[6]) + bv1.z; o1.w = di * (a[7] + b[7]) + bv1.w;
  *(float4*)&out[(size_t)i * F + base] = o0;
  *(float4*)&out[(size_t)i * F + base + 4] = o1;
}

// ---------- GEMM1: C = A[MxK] @ B[NxK]^T, +bias +relu, fp16 out ----------
// 128x128 tile, BK=64, async global_load_lds staging w/ XOR chunk swizzle,
// LDS-repacked coalesced epilogue.
__global__ __launch_bounds__(256) void gemm1_f16(
    const f16* __restrict__ A, const f16* __restrict__ B,
    const float* __restrict__ bias, f16* __restrict__ C,
    int M, int N, int K) {
  __shared__ __align__(16) f16 smem[2 * 128 * 64];  // 32 KB: sA | sB, also epilogue buffer
  f16* sA = smem;
  f16* sB = smem + 128 * 64;
  const int m0 = blockIdx.y * 128;
  const int n0 = blockIdx.x * 128;
  const int lane = threadIdx.x & 63;
  const int wave = threadIdx.x >> 6;
  const int wm = (wave & 1) * 64;
  const int wn = (wave >> 1) * 64;
  const int lrow = lane & 15;
  const int quad = lane >> 4;

  f32x4 acc[4][4];
#pragma unroll
  for (int i = 0; i < 4; ++i)
#pragma unroll
    for (int j = 0; j < 4; ++j) acc[i][j] = (f32x4)(0.f);

  for (int k0 = 0; k0 < K; k0 += 64) {
#pragma unroll
    for (int i = 0; i < 4; ++i) {
      int ch = (i * 4 + wave) * 64 + lane;
      int r = ch >> 3;
      int cg = (ch & 7) ^ (r & 7);
      int gr = min(m0 + r, M - 1);
      gload_lds16(&A[(size_t)gr * K + k0 + cg * 8], &sA[(size_t)(i * 4 + wave) * 512]);
      int gn = min(n0 + r, N - 1);
      gload_lds16(&B[(size_t)gn * K + k0 + cg * 8], &sB[(size_t)(i * 4 + wave) * 512]);
    }
    __syncthreads();
#pragma unroll
    for (int kk = 0; kk < 2; ++kk) {
      f16x8 af[4], bf[4];
      int cg = quad + kk * 4;
#pragma unroll
      for (int i = 0; i < 4; ++i) {
        int ra = wm + i * 16 + lrow;
        af[i] = *(const f16x8*)&sA[ra * 64 + ((cg ^ (ra & 7)) * 8)];
        int rb = wn + i * 16 + lrow;
        bf[i] = *(const f16x8*)&sB[rb * 64 + ((cg ^ (rb & 7)) * 8)];
      }
#pragma unroll
      for (int i = 0; i < 4; ++i)
#pragma unroll
        for (int j = 0; j < 4; ++j)
          acc[i][j] = __builtin_amdgcn_mfma_f32_16x16x32_f16(af[i], bf[j], acc[i][j], 0, 0, 0);
    }
    __syncthreads();
  }

  // epilogue: acc -> smem (f16 tile [128][128]) -> coalesced dwordx4 stores
  const int crow = quad * 4;
  const int ccol = lane & 15;
#pragma unroll
  for (int j = 0; j < 4; ++j) {
    int col = wn + j * 16 + ccol;
    int gcol = n0 + col;
    float bv = (gcol < N) ? bias[gcol] : 0.f;
#pragma unroll
    for (int i = 0; i < 4; ++i) {
#pragma unroll
      for (int r = 0; r < 4; ++r) {
        int row = wm + i * 16 + crow + r;
        smem[row * 128 + col] = (f16)fmaxf(acc[i][j][r] + bv, 0.f);
      }
    }
  }
  __syncthreads();
#pragma unroll
  for (int i = 0; i < 8; ++i) {
    int ch = i * 256 + (int)threadIdx.x;
    int r = ch >> 4;
    int cc = ch & 15;
    int grow = m0 + r;
    int gcol = n0 + cc * 8;
    if (grow < M && gcol < N)
      *(uint4*)&C[(size_t)grow * N + gcol] = *(const uint4*)&smem[r * 128 + cc * 8];
  }
}

// ---------- GEMM2: C = dinv ∘ (A[MxK] @ B[NxK]^T), fp16 out, tile 128x80 ----------
// Double-buffered async staging: one barrier per K-iter; prefetch of tile k+1
// overlaps MFMA on tile k (barrier's vmcnt(0) drain pays only residual latency).
#define G2TILE (128 * 64 + 80 * 64)
__global__ __launch_bounds__(256) void gemm2_f16(
    const f16* __restrict__ A, const f16* __restrict__ B,
    const float* __restrict__ dinv, f16* __restrict__ C,
    int M, int N, int K) {
  __shared__ __align__(16) f16 smem[2 * G2TILE];  // 52 KB

  const int mtc = (M + 127) >> 7;
  const int ntc = (N + 79) / 80;
  const int fullm = mtc & ~7;
  const int full = fullm * ntc;
  int idf = blockIdx.x;
  int mt, nt;
  if (idf < full) {
    int gsz = 8 * ntc;
    int grp = idf / gsz;
    int r = idf - grp * gsz;
    mt = grp * 8 + (r & 7);
    nt = r >> 3;
  } else {
    int r = idf - full;
    int rem = mtc - fullm;
    mt = fullm + r % rem;
    nt = r / rem;
  }
  const int m0 = mt * 128;
  const int n0 = nt * 80;
  const int lane = threadIdx.x & 63;
  const int wave = threadIdx.x >> 6;
  const int wm = wave * 32;
  const int lrow = lane & 15;
  const int quad = lane >> 4;

  f32x4 acc[2][5];
#pragma unroll
  for (int i = 0; i < 2; ++i)
#pragma unroll
    for (int j = 0; j < 5; ++j) acc[i][j] = (f32x4)(0.f);

  auto stage = [&](int k0, int buf) {
    f16* sA = smem + buf * G2TILE;
    f16* sB = sA + 128 * 64;
#pragma unroll
    for (int i = 0; i < 4; ++i) {
      int ch = (i * 4 + wave) * 64 + lane;
      int r = ch >> 3;
      int cg = (ch & 7) ^ (r & 7);
      int gr = min(m0 + r, M - 1);
      gload_lds16(&A[(size_t)gr * K + k0 + cg * 8], &sA[(size_t)(i * 4 + wave) * 512]);
    }
#pragma unroll
    for (int i = 0; i < 3; ++i) {
      if (i * 4 + wave < 10) {  // 640 chunks, wave-uniform guard
        int ch = (i * 4 + wave) * 64 + lane;
        int r = ch >> 3;
        int cg = (ch & 7) ^ (r & 7);
        int gn = min(n0 + r, N - 1);
        gload_lds16(&B[(size_t)gn * K + k0 + cg * 8], &sB[(size_t)(i * 4 + wave) * 512]);
      }
    }
  };

  stage(0, 0);
  int buf = 0;
  for (int k0 = 0; k0 < K; k0 += 64) {
    __syncthreads();  // implicit vmcnt(0): buffer `buf` is ready; prev compute done
    if (k0 + 64 < K) stage(k0 + 64, buf ^ 1);
    const f16* sA = smem + buf * G2TILE;
    const f16* sB = sA + 128 * 64;
#pragma unroll
    for (int kk = 0; kk < 2; ++kk) {
      f16x8 af[2], bf[5];
      int cg = quad + kk * 4;
#pragma unroll
      for (int i = 0; i < 2; ++i) {
        int ra = wm + i * 16 + lrow;
        af[i] = *(const f16x8*)&sA[ra * 64 + ((cg ^ (ra & 7)) * 8)];
      }
#pragma unroll
      for (int j = 0; j < 5; ++j) {
        int rb = j * 16 + lrow;
        bf[j] = *(const f16x8*)&sB[rb * 64 + ((cg ^ (rb & 7)) * 8)];
      }
#pragma unroll
      for (int i = 0; i < 2; ++i)
#pragma unroll
        for (int j = 0; j < 5; ++j)
          acc[i][j] = __builtin_amdgcn_mfma_f32_16x16x32_f16(af[i], bf[j], acc[i][j], 0, 0, 0);
    }
    buf ^= 1;
  }

  __syncthreads();  // all waves done reading smem before epilogue reuse
  // epilogue: scale rows by dinv, pack to smem [128][80], coalesced stores
  const int crow = quad * 4;
  const int ccol = lane & 15;
  float dsc[2][4];
#pragma unroll
  for (int i = 0; i < 2; ++i)
#pragma unroll
    for (int r = 0; r < 4; ++r) {
      int grow = m0 + wm + i * 16 + crow + r;
      dsc[i][r] = dinv[min(grow, M - 1)];
    }
#pragma unroll
  for (int j = 0; j < 5; ++j) {
    int col = j * 16 + ccol;
#pragma unroll
    for (int i = 0; i < 2; ++i) {
#pragma unroll
      for (int r = 0; r < 4; ++r) {
        int row = wm + i * 16 + crow + r;
        smem[row * 80 + col] = (f16)(acc[i][j][r] * dsc[i][r]);
      }
    }
  }
  __syncthreads();
#pragma unroll
  for (int i = 0; i < 5; ++i) {
    int ch = i * 256 + (int)threadIdx.x;  // of 1280 chunks (10 per row)
    int r = ch / 10;
    int rem = ch - 10 * r;
    int grow = m0 + r;
    if (grow < M)
      *(uint4*)&C[(size_t)grow * N + n0 + rem * 8] = *(const uint4*)&smem[r * 80 + rem * 8];
  }
}

extern "C" void kernel_launch(void* const* d_in, const int* in_sizes, int n_in,
                              void* d_out, int out_size, void* d_ws, size_t ws_size,
                              hipStream_t stream) {
  const float* x = (const float*)d_in[0];
  const void* edges = d_in[1];
  const float* W1 = (const float*)d_in[2];
  const float* b1 = (const float*)d_in[3];
  const float* W2 = (const float*)d_in[4];
  const float* b2 = (const float*)d_in[5];
  float* out = (float*)d_out;

  const int N1 = in_sizes[3];       // 1600
  const int N2 = in_sizes[5];       // 400
  const int K1 = in_sizes[2] / N1;  // 256
  const int K2 = in_sizes[4] / N2;  // 1600
  const int n = in_sizes[0] / K1;   // 20000
  const int E = in_sizes[1] / 2;    // 320000

  char* ws = (char*)d_ws;
  size_t o = 0;
  auto take = [&](size_t bytes) {
    char* p = ws + o;
    o += (bytes + 255) & ~(size_t)255;
    return p;
  };
  int* indeg = (int*)take((size_t)n * 4);
  int* cursor = (int*)take((size_t)n * 4);
  int* flag = (int*)take(4);
  size_t zero_bytes = o;
  int* rowptr = (int*)take((size_t)(n + 1) * 4);
  int* colsrc = (int*)take((size_t)E * 4);
  float* dinv = (float*)take((size_t)n * 4);
  int* bsum = (int*)take(64 * 4);
  f16* xs = (f16*)take((size_t)n * K1 * 2);    // 10 MB (dinv-premultiplied x)
  f16* xa = (f16*)take((size_t)n * K1 * 2);    // 10 MB
  f16* w1t = (f16*)take((size_t)K1 * N1 * 2);  // 0.8 MB
  f16* w2t = (f16*)take((size_t)K2 * N2 * 2);  // 1.3 MB
  f16* h = (f16*)take((size_t)n * N1 * 2);     // 64 MB
  f16* g = (f16*)take((size_t)n * N2 * 2);     // 16 MB (dinv-premultiplied)

  hipMemsetAsync(d_ws, 0, zero_bytes, stream);

  const int nb = (n + 1023) / 1024;  // 20 <= 64
  const int castBlocks = (K1 * N1 + K2 * N2 + 255) / 256;
  const int sb = (E + 255) / 256;
  const int xcastBlocks = (n * 64 + 255) / 256;

  detect_castT_kernel<<<1 + castBlocks, 256, 0, stream>>>((const unsigned int*)edges, flag, W1,
                                                          w1t, K1, N1, W2, w2t, K2, N2);
  deg_kernel<<<sb, 256, 0, stream>>>(edges, flag, indeg, E);
  scan1_kernel<<<nb, 1024, 0, stream>>>(indeg, dinv, bsum, n);
  scan3_kernel<<<nb, 1024, 0, stream>>>(indeg, bsum, rowptr, n, nb);
  scatter_xcast_kernel<<<sb + xcastBlocks, 256, 0, stream>>>(edges, flag, rowptr, cursor, colsrc,
                                                             E, sb, x, dinv, xs, n);

  // Layer 1: aggregate at 256 dims (fp16), GEMM (+b1, relu, fp16 out)
  agg1_kernel<<<(n + 3) / 4, 256, 0, stream>>>(xs, dinv, rowptr, colsrc, xa, n);
  {
    dim3 grid((N1 + 127) / 128, (n + 127) / 128);
    gemm1_f16<<<grid, 256, 0, stream>>>(xa, w1t, b1, h, n, N1, K1);
  }
  // Layer 2: GEMM (dinv-scaled fp16 out, 128x80 dbuf tiles), then aggregate (+b2, fp32 out)
  {
    int mtc = (n + 127) / 128;
    int ntc = (N2 + 79) / 80;
    gemm2_f16<<<mtc * ntc, 256, 0, stream>>>(h, w2t, dinv, g, n, N2, K2);
  }
  agg2_kernel<<<(n + 3) / 4, 256, 0, stream>>>(g, dinv, rowptr, colsrc, b2, out, n, N2);
}